// Round 8
// baseline (766.395 us; speedup 1.0000x reference)
//
#include <hip/hip_runtime.h>
#include <cstdint>

#define N_NODES 100000
#define N_EDGES 1600000
#define F 128
#define OUT_CLS 40
#define FM 128     // rows per fused block (4 waves x 32)
#define BSHIFT 10  // coarse bucket = dst >> 10 (1024 nodes)
#define NBUCK 98   // ceil(100000/1024)
#define TILE 2048  // edges per k_bscatter block

using f32x16 = __attribute__((ext_vector_type(16))) float;
using bf16x8 = __attribute__((ext_vector_type(8))) short;
using f16x2 = __attribute__((ext_vector_type(2))) _Float16;

// ---- edge accessor: flag=1 means int64 storage (little-endian low word at 2*idx) ----
__device__ __forceinline__ int edge_val(const int* eb, int is64, long idx) {
  return is64 ? eb[2 * idx] : eb[idx];
}

__global__ void k_detect(const unsigned int* eb, int* flag) {
  if (threadIdx.x == 0 && blockIdx.x == 0) {
    int is64 = 1;
#pragma unroll
    for (int i = 1; i < 16; i += 2) is64 &= (eb[i] == 0u);
    flag[0] = is64;
  }
}

// coarse histogram: 98 buckets via LDS, one global atomic per bucket per block
#define CH_E 16
__global__ __launch_bounds__(256) void k_chist(const int* __restrict__ eb, const int* __restrict__ flag,
                                               int* __restrict__ bhist) {
  __shared__ int lh[NBUCK];
  int t = threadIdx.x;
  if (t < NBUCK) lh[t] = 0;
  __syncthreads();
  int is64 = flag[0];
  long base = (long)blockIdx.x * (256 * CH_E);
#pragma unroll
  for (int i = 0; i < CH_E; ++i) {
    long e = base + (long)i * 256 + t;
    if (e < N_EDGES) {
      int d = edge_val(eb, is64, (long)N_EDGES + e);
      atomicAdd(&lh[d >> BSHIFT], 1);
    }
  }
  __syncthreads();
  if (t < NBUCK && lh[t]) atomicAdd(&bhist[t], lh[t]);
}

// scan 98 bucket sums -> boff[0..98]; init bkt_cursor; off[N_NODES]=N_EDGES
__global__ __launch_bounds__(128) void k_bscan(const int* __restrict__ bhist, int* __restrict__ boff,
                                               int* __restrict__ bkt_cursor, int* __restrict__ off) {
  __shared__ int sh[128];
  int t = threadIdx.x;
  int v = (t < NBUCK) ? bhist[t] : 0;
  sh[t] = v;
  __syncthreads();
  for (int d = 1; d < 128; d <<= 1) {
    int u = (t >= d) ? sh[t - d] : 0;
    __syncthreads();
    sh[t] += u;
    __syncthreads();
  }
  int incl = sh[t];
  if (t < NBUCK) {
    boff[t] = incl - v;
    bkt_cursor[t] = incl - v;
  }
  if (t == NBUCK - 1) boff[NBUCK] = incl;
  if (t == 0) off[N_NODES] = N_EDGES;
}

// coarse scatter: LDS counting-sort a 2048-edge tile by bucket, reserve per-bucket global
// runs (one atomic/bucket/tile), copy out coalesced. ebuf entry packed: src | (dst&1023)<<17
__global__ __launch_bounds__(256) void k_bscatter(const int* __restrict__ eb, const int* __restrict__ flag,
                                                  int* __restrict__ bkt_cursor, unsigned* __restrict__ ebuf) {
  __shared__ int lhist[128];
  __shared__ int lbase[128];
  __shared__ int gbase[NBUCK];
  __shared__ int lcnt[NBUCK];
  __shared__ unsigned buf[TILE];
  __shared__ int slotpos[TILE];
  int t = threadIdx.x;
  long e0 = (long)blockIdx.x * TILE;
  int is64 = flag[0];
  if (t < 128) lhist[t] = 0;
  __syncthreads();
#pragma unroll
  for (int i = 0; i < TILE / 256; ++i) {
    long e = e0 + t + i * 256;
    if (e < N_EDGES) {
      int d = edge_val(eb, is64, (long)N_EDGES + e);
      atomicAdd(&lhist[d >> BSHIFT], 1);
    }
  }
  __syncthreads();
  if (t < 128) lbase[t] = lhist[t];
  __syncthreads();
  for (int d = 1; d < 128; d <<= 1) {
    int v = (t >= d && t < 128) ? lbase[t - d] : 0;
    __syncthreads();
    if (t < 128) lbase[t] += v;
    __syncthreads();
  }
  if (t < NBUCK) {
    gbase[t] = atomicAdd(&bkt_cursor[t], lhist[t]);
    lcnt[t] = 0;
  }
  __syncthreads();
#pragma unroll
  for (int i = 0; i < TILE / 256; ++i) {
    long e = e0 + t + i * 256;
    if (e < N_EDGES) {
      int d = edge_val(eb, is64, (long)N_EDGES + e);
      int s = edge_val(eb, is64, e);
      int b = d >> BSHIFT;
      int n = atomicAdd(&lcnt[b], 1);
      int slot = lbase[b] - lhist[b] + n;
      buf[slot] = (unsigned)s | ((unsigned)(d & 1023) << 17);
      slotpos[slot] = gbase[b] + n;
    }
  }
  __syncthreads();
  int tile_n = (int)min((long)TILE, (long)N_EDGES - e0);
  for (int i = t; i < tile_n; i += 256) {
    ebuf[slotpos[i]] = buf[i];
  }
}

// per-bucket fine sort: LDS 1024-bin histogram + wave-shuffle scan -> off[node], then
// LDS-cursor scatter of srcs. Packed ebuf: d10 = e>>17, src = e & 0x1FFFF.
__global__ __launch_bounds__(1024) void k_fsort(const unsigned* __restrict__ ebuf, const int* __restrict__ boff,
                                                int* __restrict__ off, int* __restrict__ srcs) {
  __shared__ int hist[1024];
  __shared__ int cur[1024];
  __shared__ int wsum[16];
  int b = blockIdx.x;
  int t = threadIdx.x;
  int p0 = boff[b], p1 = boff[b + 1];
  hist[t] = 0;
  __syncthreads();
  for (int p = p0 + t; p < p1; p += 1024) {
    int d = (int)(ebuf[p] >> 17);
    atomicAdd(&hist[d], 1);
  }
  __syncthreads();
  // exclusive scan of hist[0..1024): per-wave shfl scan + wave-total scan
  int h = hist[t];
  int v = h;
#pragma unroll
  for (int o = 1; o < 64; o <<= 1) {
    int u = __shfl_up(v, o);
    if ((t & 63) >= o) v += u;
  }
  if ((t & 63) == 63) wsum[t >> 6] = v;
  __syncthreads();
  if (t < 64) {
    int w = (t < 16) ? wsum[t] : 0;
#pragma unroll
    for (int o = 1; o < 16; o <<= 1) {
      int u = __shfl_up(w, o);
      if (t >= o) w += u;
    }
    if (t < 16) wsum[t] = w;
  }
  __syncthreads();
  int base = (t >> 6) ? wsum[(t >> 6) - 1] : 0;
  int gpos = p0 + base + v - h;  // exclusive prefix
  int node = (b << BSHIFT) + t;
  if (node < N_NODES) off[node] = gpos;
  cur[t] = gpos;
  __syncthreads();
  for (int p = p0 + t; p < p1; p += 1024) {
    unsigned e = ebuf[p];
    int pos = atomicAdd(&cur[(int)(e >> 17)], 1);
    srcs[pos] = (int)(e & 0x1FFFFu);
  }
}

// fp32 -> fp16 copy (RN), 8 elems/thread, row-major
__global__ __launch_bounds__(256) void k_tohalf(const float* __restrict__ in, _Float16* __restrict__ o) {
  int i = blockIdx.x * 256 + threadIdx.x;
  if (i >= N_NODES * F / 8) return;
  float4 a = reinterpret_cast<const float4*>(in)[2 * i];
  float4 b = reinterpret_cast<const float4*>(in)[2 * i + 1];
  union {
    _Float16 h[8];
    uint4 u;
  } r;
  r.h[0] = (_Float16)a.x; r.h[1] = (_Float16)a.y; r.h[2] = (_Float16)a.z; r.h[3] = (_Float16)a.w;
  r.h[4] = (_Float16)b.x; r.h[5] = (_Float16)b.y; r.h[6] = (_Float16)b.z; r.h[7] = (_Float16)b.w;
  reinterpret_cast<uint4*>(o)[i] = r.u;
}

// ---- split fp32 -> bf16 hi/lo (truncation; lo compensates, net rel err ~3*2^-16) ----
__device__ __forceinline__ void split_pack(const float4& a, const float4& b, bf16x8& hi, bf16x8& lo) {
  float f[8] = {a.x, a.y, a.z, a.w, b.x, b.y, b.z, b.w};
#pragma unroll
  for (int i = 0; i < 8; ++i) {
    union { float f; unsigned u; } u0;
    u0.f = f[i];
    hi[i] = (short)(u0.u >> 16);
    union { unsigned u; float f; } uh;
    uh.u = u0.u & 0xFFFF0000u;
    union { float f; unsigned u; } ur;
    ur.f = f[i] - uh.f;
    lo[i] = (short)(ur.u >> 16);
  }
}

// pre-split weights: Wl/Wr per layer -> wsp[layer][4][128*128] bf16 (WlH, WlL, WrH, WrL)
__global__ __launch_bounds__(256) void k_wsplit(const float* __restrict__ Wl1, const float* __restrict__ Wr1,
                                                const float* __restrict__ Wl2, const float* __restrict__ Wr2,
                                                const float* __restrict__ Wl3, const float* __restrict__ Wr3,
                                                unsigned short* __restrict__ wsp) {
  int e = blockIdx.x * 256 + threadIdx.x;  // 0..49151
  if (e >= 3 * 16384) return;
  int L = e >> 14, off = e & 16383;
  const float* wl = (L == 0) ? Wl1 : (L == 1) ? Wl2 : Wl3;
  const float* wr = (L == 0) ? Wr1 : (L == 1) ? Wr2 : Wr3;
  unsigned short* base = wsp + (size_t)L * 4 * 16384;
  {
    union { float f; unsigned u; } u0;
    u0.f = wl[off];
    union { unsigned u; float f; } uh;
    uh.u = u0.u & 0xFFFF0000u;
    union { float f; unsigned u; } ur;
    ur.f = u0.f - uh.f;
    base[off] = (unsigned short)(u0.u >> 16);
    base[16384 + off] = (unsigned short)(ur.u >> 16);
  }
  {
    union { float f; unsigned u; } u0;
    u0.f = wr[off];
    union { unsigned u; float f; } uh;
    uh.u = u0.u & 0xFFFF0000u;
    union { float f; unsigned u; } ur;
    ur.f = u0.f - uh.f;
    base[2 * 16384 + off] = (unsigned short)(u0.u >> 16);
    base[3 * 16384 + off] = (unsigned short)(ur.u >> 16);
  }
}

// Fused SAGE layer: phase 1 gathers the 128-row mean tile into LDS (R3's proven readlane
// gather, one wave per node); phase 2 is the split-bf16 MFMA linear with A from LDS and
// weights read directly from L2-resident wsp (no weight LDS -> 67.6KB LDS -> 2 blocks/CU,
// so one block's MFMA/store phase overlaps the co-resident block's fetch-bound gather).
__global__ __launch_bounds__(256, 2) void k_fused(const _Float16* __restrict__ x16, const float* __restrict__ x,
                                                  const int* __restrict__ off, const int* __restrict__ srcs,
                                                  const unsigned short* __restrict__ wsp,  // [4][128][128]
                                                  const float* __restrict__ bl, float* __restrict__ out,
                                                  _Float16* __restrict__ out16, int relu) {
  __shared__ float agg_s[FM][132];  // 528B row stride: 16B-aligned, 4-way max on b128 reads
  int tid = threadIdx.x;
  int wid = tid >> 6, lane = tid & 63;
  long rb = (long)blockIdx.x * FM;

  // ---- phase 1: each wave gathers 32 nodes (lane owns feats 2l,2l+1) ----
  for (int i = 0; i < 32; ++i) {
    long n = rb + wid * 32 + i;
    if (n >= N_NODES) break;
    int p0 = off[n], p1 = off[n + 1];
    int deg = p1 - p0;
    float sx = 0.f, sy = 0.f;
    for (int base = 0; base < deg; base += 64) {
      int rem = deg - base;
      int cnt = (rem < 64) ? rem : 64;
      int my = (lane < cnt) ? srcs[p0 + base + lane] : 0;
      int j = 0;
      for (; j + 7 < cnt; j += 8) {
        int s[8];
#pragma unroll
        for (int k = 0; k < 8; ++k) s[k] = __builtin_amdgcn_readlane(my, j + k);
        f16x2 v[8];
#pragma unroll
        for (int k = 0; k < 8; ++k)
          v[k] = *reinterpret_cast<const f16x2*>(x16 + (size_t)(unsigned)s[k] * F + 2 * lane);
#pragma unroll
        for (int k = 0; k < 8; ++k) {
          sx += (float)v[k][0];
          sy += (float)v[k][1];
        }
      }
      for (; j + 3 < cnt; j += 4) {
        int s[4];
#pragma unroll
        for (int k = 0; k < 4; ++k) s[k] = __builtin_amdgcn_readlane(my, j + k);
        f16x2 v[4];
#pragma unroll
        for (int k = 0; k < 4; ++k)
          v[k] = *reinterpret_cast<const f16x2*>(x16 + (size_t)(unsigned)s[k] * F + 2 * lane);
#pragma unroll
        for (int k = 0; k < 4; ++k) {
          sx += (float)v[k][0];
          sy += (float)v[k][1];
        }
      }
      for (; j < cnt; ++j) {
        int s = __builtin_amdgcn_readlane(my, j);
        f16x2 v = *reinterpret_cast<const f16x2*>(x16 + (size_t)(unsigned)s * F + 2 * lane);
        sx += (float)v[0];
        sy += (float)v[1];
      }
    }
    float inv = 1.0f / (float)max(deg, 1);
    float2 r;
    r.x = sx * inv;
    r.y = sy * inv;
    *reinterpret_cast<float2*>(&agg_s[wid * 32 + i][2 * lane]) = r;
  }
  __syncthreads();

  // ---- phase 2: 32-row MFMA tile per wave; A from LDS, weights from L2 ----
  int l31 = lane & 31, lhi = lane >> 5;
  int lrow = wid * 32 + l31;
  long rbw = rb + wid * 32;
  int r0 = (int)min(rbw + l31, (long)N_NODES - 1);
  const float* x0p = x + (size_t)r0 * F + lhi * 8;

  f32x16 acc[4];
#pragma unroll
  for (int ct = 0; ct < 4; ++ct) acc[ct] = (f32x16)0.f;

  float4 xp = *reinterpret_cast<const float4*>(x0p);
  float4 xq = *reinterpret_cast<const float4*>(x0p + 4);

#pragma unroll
  for (int ks = 0; ks < 8; ++ks) {
    float4 xp_n, xq_n;
    if (ks < 7) {
      const float* xn = x0p + (ks + 1) * 16;
      xp_n = *reinterpret_cast<const float4*>(xn);
      xq_n = *reinterpret_cast<const float4*>(xn + 4);
    }
    int k0 = ks * 16 + lhi * 8;
    float4 ap = *reinterpret_cast<const float4*>(&agg_s[lrow][k0]);
    float4 aq = *reinterpret_cast<const float4*>(&agg_s[lrow][k0 + 4]);
    bf16x8 aH0, aL0, xH0, xL0;
    split_pack(ap, aq, aH0, aL0);
    split_pack(xp, xq, xH0, xL0);
#pragma unroll
    for (int ct = 0; ct < 4; ++ct) {
      int j = ct * 32 + l31;
      const unsigned short* wb = wsp + (size_t)j * 128 + k0;
      bf16x8 BlH = *reinterpret_cast<const bf16x8*>(wb);
      bf16x8 BlL = *reinterpret_cast<const bf16x8*>(wb + 16384);
      bf16x8 BrH = *reinterpret_cast<const bf16x8*>(wb + 2 * 16384);
      bf16x8 BrL = *reinterpret_cast<const bf16x8*>(wb + 3 * 16384);
      acc[ct] = __builtin_amdgcn_mfma_f32_32x32x16_bf16(aH0, BlH, acc[ct], 0, 0, 0);
      acc[ct] = __builtin_amdgcn_mfma_f32_32x32x16_bf16(aL0, BlH, acc[ct], 0, 0, 0);
      acc[ct] = __builtin_amdgcn_mfma_f32_32x32x16_bf16(aH0, BlL, acc[ct], 0, 0, 0);
      acc[ct] = __builtin_amdgcn_mfma_f32_32x32x16_bf16(xH0, BrH, acc[ct], 0, 0, 0);
      acc[ct] = __builtin_amdgcn_mfma_f32_32x32x16_bf16(xL0, BrH, acc[ct], 0, 0, 0);
      acc[ct] = __builtin_amdgcn_mfma_f32_32x32x16_bf16(xH0, BrL, acc[ct], 0, 0, 0);
    }
    xp = xp_n;
    xq = xq_n;
  }

  // epilogue: +bias, row L2-norm across 32 lanes (same lhi), optional relu, masked store (+fp16 copy).
#pragma unroll
  for (int ct = 0; ct < 4; ++ct) {
    float b = bl[ct * 32 + l31];
#pragma unroll
    for (int i = 0; i < 16; ++i) acc[ct][i] += b;
  }
#pragma unroll
  for (int i = 0; i < 16; ++i) {
    float ss = acc[0][i] * acc[0][i] + acc[1][i] * acc[1][i] +
               acc[2][i] * acc[2][i] + acc[3][i] * acc[3][i];
#pragma unroll
    for (int o = 1; o < 32; o <<= 1) ss += __shfl_xor(ss, o);
    float inv = 1.0f / fmaxf(sqrtf(ss), 1e-12f);
    long grow = rbw + (i & 3) + 8 * (i >> 2) + 4 * lhi;
    if (grow < N_NODES) {
      long base = grow * F + l31;
#pragma unroll
      for (int ct = 0; ct < 4; ++ct) {
        float v = acc[ct][i] * inv;
        if (relu) v = fmaxf(v, 0.f);
        out[base + ct * 32] = v;
        if (out16) out16[base + ct * 32] = (_Float16)v;
      }
    }
  }
}

// 32 nodes/block (grid = N_NODES/32 = 3125); Wfc + h tile in LDS; 8 threads/node x 5 classes
#define FCP 132
__global__ __launch_bounds__(256) void k_fc_softmax(const float* __restrict__ h, const float* __restrict__ Wfc,
                                                    const float* __restrict__ bfc, float* __restrict__ out) {
  __shared__ float w_s[OUT_CLS][FCP];
  __shared__ float h_s[32][FCP];
  int tid = threadIdx.x;
  int nb = blockIdx.x * 32;

  for (int i = tid; i < OUT_CLS * (F / 4); i += 256) {
    int r = i >> 5, c = (i & 31) * 4;
    *reinterpret_cast<float4*>(&w_s[r][c]) = *reinterpret_cast<const float4*>(Wfc + (size_t)r * F + c);
  }
  for (int i = tid; i < 32 * (F / 4); i += 256) {
    int r = i >> 5, c = (i & 31) * 4;
    *reinterpret_cast<float4*>(&h_s[r][c]) = *reinterpret_cast<const float4*>(h + (size_t)(nb + r) * F + c);
  }
  __syncthreads();

  int r = tid >> 3, sub = tid & 7;
  float acc[5];
#pragma unroll
  for (int c = 0; c < 5; ++c) acc[c] = bfc[sub * 5 + c];

  for (int k4 = 0; k4 < F / 4; ++k4) {
    float4 hv = *reinterpret_cast<const float4*>(&h_s[r][k4 * 4]);
#pragma unroll
    for (int c = 0; c < 5; ++c) {
      float4 wv = *reinterpret_cast<const float4*>(&w_s[sub * 5 + c][k4 * 4]);
      acc[c] += hv.x * wv.x + hv.y * wv.y + hv.z * wv.z + hv.w * wv.w;
    }
  }

  float m = acc[0];
#pragma unroll
  for (int c = 1; c < 5; ++c) m = fmaxf(m, acc[c]);
#pragma unroll
  for (int o = 4; o > 0; o >>= 1) m = fmaxf(m, __shfl_xor(m, o));
  float e[5], s = 0.f;
#pragma unroll
  for (int c = 0; c < 5; ++c) {
    e[c] = expf(acc[c] - m);
    s += e[c];
  }
#pragma unroll
  for (int o = 4; o > 0; o >>= 1) s += __shfl_xor(s, o);
  float inv = 1.0f / s;
#pragma unroll
  for (int c = 0; c < 5; ++c) out[(size_t)(nb + r) * OUT_CLS + sub * 5 + c] = e[c] * inv;
}

extern "C" void kernel_launch(void* const* d_in, const int* in_sizes, int n_in, void* d_out, int out_size,
                              void* d_ws, size_t ws_size, hipStream_t stream) {
  const float* feat = (const float*)d_in[0];
  const int* eb = (const int*)d_in[1];
  const float* Wl1 = (const float*)d_in[2];
  const float* bl1 = (const float*)d_in[3];
  const float* Wr1 = (const float*)d_in[4];
  const float* Wl2 = (const float*)d_in[5];
  const float* bl2 = (const float*)d_in[6];
  const float* Wr2 = (const float*)d_in[7];
  const float* Wl3 = (const float*)d_in[8];
  const float* bl3 = (const float*)d_in[9];
  const float* Wr3 = (const float*)d_in[10];
  const float* Wfc = (const float*)d_in[11];
  const float* bfc = (const float*)d_in[12];
  float* out = (float*)d_out;

  char* w = (char*)d_ws;
  auto alloc = [&](size_t bytes) {
    char* p = w;
    w += (bytes + 255) & ~(size_t)255;
    return p;
  };
  int* flag = (int*)alloc(4);
  int* bhist = (int*)alloc((size_t)NBUCK * 4);
  int* boff = (int*)alloc((size_t)(NBUCK + 1) * 4);
  int* off = (int*)alloc((size_t)(N_NODES + 1) * 4);
  int* srcs = (int*)alloc((size_t)N_EDGES * 4 + 256);  // +pad
  int* bkt_cursor = (int*)alloc((size_t)NBUCK * 4);
  unsigned short* wsp = (unsigned short*)alloc((size_t)3 * 4 * 16384 * 2);
  float* bufA = (float*)alloc((size_t)N_NODES * F * 4);
  float* bufB = (float*)alloc((size_t)N_NODES * F * 4);
  _Float16* h16X = (_Float16*)alloc((size_t)N_NODES * F * 2);  // feat16, later h2_16
  _Float16* h16A = (_Float16*)alloc((size_t)N_NODES * F * 2);  // h1_16
  unsigned* ebuf = (unsigned*)bufB;  // dead before bufB's first use (layer-2 fused output)
  (void)ws_size;
  (void)in_sizes;
  (void)n_in;
  (void)out_size;

  hipMemsetAsync(bhist, 0, (size_t)NBUCK * 4, stream);
  k_detect<<<1, 64, 0, stream>>>((const unsigned int*)eb, flag);
  k_chist<<<(N_EDGES + 256 * CH_E - 1) / (256 * CH_E), 256, 0, stream>>>(eb, flag, bhist);
  k_bscan<<<1, 128, 0, stream>>>(bhist, boff, bkt_cursor, off);
  k_bscatter<<<(N_EDGES + TILE - 1) / TILE, 256, 0, stream>>>(eb, flag, bkt_cursor, ebuf);
  k_fsort<<<NBUCK, 1024, 0, stream>>>(ebuf, boff, off, srcs);
  k_wsplit<<<192, 256, 0, stream>>>(Wl1, Wr1, Wl2, Wr2, Wl3, Wr3, wsp);
  k_tohalf<<<(N_NODES * F / 8 + 255) / 256, 256, 0, stream>>>(feat, h16X);

  const int nfu = (N_NODES + FM - 1) / FM;  // 782 (2 blocks/CU co-resident)
  const int nfc = N_NODES / 32;             // 3125

  // layer 1: gather from h16X(feat16), x=feat -> bufA (+h16A)
  k_fused<<<nfu, 256, 0, stream>>>(h16X, feat, off, srcs, wsp + 0 * 4 * 16384, bl1, bufA, h16A, 1);
  // layer 2: gather from h16A, x=bufA -> bufB (+h16X reused as h2_16)
  k_fused<<<nfu, 256, 0, stream>>>(h16A, bufA, off, srcs, wsp + 1 * 4 * 16384, bl2, bufB, h16X, 1);
  // layer 3: gather from h16X, x=bufB -> bufA
  k_fused<<<nfu, 256, 0, stream>>>(h16X, bufB, off, srcs, wsp + 2 * 4 * 16384, bl3, bufA, ((_Float16*)0), 0);
  // FC + softmax
  k_fc_softmax<<<nfc, 256, 0, stream>>>(bufA, Wfc, bfc, out);
}

// Round 9
// 395.579 us; speedup vs baseline: 1.9374x; 1.9374x over previous
//
#include <hip/hip_runtime.h>
#include <cstdint>

#define N_NODES 100000
#define N_EDGES 1600000
#define F 128
#define OUT_CLS 40
#define LW 13          // waves per k_linear block
#define LBM (LW * 32)  // 416 rows per block -> grid 241 <= 256 CUs (single round)
#define BSHIFT 10      // coarse bucket = dst >> 10 (1024 nodes)
#define NBUCK 98       // ceil(100000/1024)
#define TILE 2048      // edges per k_bscatter block

using f32x16 = __attribute__((ext_vector_type(16))) float;
using bf16x8 = __attribute__((ext_vector_type(8))) short;
using f16x2 = __attribute__((ext_vector_type(2))) _Float16;
using f16x8 = __attribute__((ext_vector_type(8))) _Float16;

// ---- edge accessor: flag=1 means int64 storage (little-endian low word at 2*idx) ----
__device__ __forceinline__ int edge_val(const int* eb, int is64, long idx) {
  return is64 ? eb[2 * idx] : eb[idx];
}

__global__ void k_detect(const unsigned int* eb, int* flag) {
  if (threadIdx.x == 0 && blockIdx.x == 0) {
    int is64 = 1;
#pragma unroll
    for (int i = 1; i < 16; i += 2) is64 &= (eb[i] == 0u);
    flag[0] = is64;
  }
}

// coarse histogram: 98 buckets via LDS, one global atomic per bucket per block
#define CH_E 16
__global__ __launch_bounds__(256) void k_chist(const int* __restrict__ eb, const int* __restrict__ flag,
                                               int* __restrict__ bhist) {
  __shared__ int lh[NBUCK];
  int t = threadIdx.x;
  if (t < NBUCK) lh[t] = 0;
  __syncthreads();
  int is64 = flag[0];
  long base = (long)blockIdx.x * (256 * CH_E);
#pragma unroll
  for (int i = 0; i < CH_E; ++i) {
    long e = base + (long)i * 256 + t;
    if (e < N_EDGES) {
      int d = edge_val(eb, is64, (long)N_EDGES + e);
      atomicAdd(&lh[d >> BSHIFT], 1);
    }
  }
  __syncthreads();
  if (t < NBUCK && lh[t]) atomicAdd(&bhist[t], lh[t]);
}

// scan 98 bucket sums -> boff[0..98]; init bkt_cursor; off[N_NODES]=N_EDGES
__global__ __launch_bounds__(128) void k_bscan(const int* __restrict__ bhist, int* __restrict__ boff,
                                               int* __restrict__ bkt_cursor, int* __restrict__ off) {
  __shared__ int sh[128];
  int t = threadIdx.x;
  int v = (t < NBUCK) ? bhist[t] : 0;
  sh[t] = v;
  __syncthreads();
  for (int d = 1; d < 128; d <<= 1) {
    int u = (t >= d) ? sh[t - d] : 0;
    __syncthreads();
    sh[t] += u;
    __syncthreads();
  }
  int incl = sh[t];
  if (t < NBUCK) {
    boff[t] = incl - v;
    bkt_cursor[t] = incl - v;
  }
  if (t == NBUCK - 1) boff[NBUCK] = incl;
  if (t == 0) off[N_NODES] = N_EDGES;
}

// coarse scatter: LDS counting-sort a 2048-edge tile by bucket, reserve per-bucket global
// runs (one atomic/bucket/tile), copy out coalesced. ebuf entry packed: src | (dst&1023)<<17
__global__ __launch_bounds__(256) void k_bscatter(const int* __restrict__ eb, const int* __restrict__ flag,
                                                  int* __restrict__ bkt_cursor, unsigned* __restrict__ ebuf) {
  __shared__ int lhist[128];
  __shared__ int lbase[128];
  __shared__ int gbase[NBUCK];
  __shared__ int lcnt[NBUCK];
  __shared__ unsigned buf[TILE];
  __shared__ int slotpos[TILE];
  int t = threadIdx.x;
  long e0 = (long)blockIdx.x * TILE;
  int is64 = flag[0];
  if (t < 128) lhist[t] = 0;
  __syncthreads();
#pragma unroll
  for (int i = 0; i < TILE / 256; ++i) {
    long e = e0 + t + i * 256;
    if (e < N_EDGES) {
      int d = edge_val(eb, is64, (long)N_EDGES + e);
      atomicAdd(&lhist[d >> BSHIFT], 1);
    }
  }
  __syncthreads();
  if (t < 128) lbase[t] = lhist[t];
  __syncthreads();
  for (int d = 1; d < 128; d <<= 1) {
    int v = (t >= d && t < 128) ? lbase[t - d] : 0;
    __syncthreads();
    if (t < 128) lbase[t] += v;
    __syncthreads();
  }
  if (t < NBUCK) {
    gbase[t] = atomicAdd(&bkt_cursor[t], lhist[t]);
    lcnt[t] = 0;
  }
  __syncthreads();
#pragma unroll
  for (int i = 0; i < TILE / 256; ++i) {
    long e = e0 + t + i * 256;
    if (e < N_EDGES) {
      int d = edge_val(eb, is64, (long)N_EDGES + e);
      int s = edge_val(eb, is64, e);
      int b = d >> BSHIFT;
      int n = atomicAdd(&lcnt[b], 1);
      int slot = lbase[b] - lhist[b] + n;
      buf[slot] = (unsigned)s | ((unsigned)(d & 1023) << 17);
      slotpos[slot] = gbase[b] + n;
    }
  }
  __syncthreads();
  int tile_n = (int)min((long)TILE, (long)N_EDGES - e0);
  for (int i = t; i < tile_n; i += 256) {
    ebuf[slotpos[i]] = buf[i];
  }
}

// per-bucket fine sort: LDS 1024-bin histogram + wave-shuffle scan -> off[node], then
// LDS-cursor scatter of srcs. Packed ebuf: d10 = e>>17, src = e & 0x1FFFF.
__global__ __launch_bounds__(1024) void k_fsort(const unsigned* __restrict__ ebuf, const int* __restrict__ boff,
                                                int* __restrict__ off, int* __restrict__ srcs) {
  __shared__ int hist[1024];
  __shared__ int cur[1024];
  __shared__ int wsum[16];
  int b = blockIdx.x;
  int t = threadIdx.x;
  int p0 = boff[b], p1 = boff[b + 1];
  hist[t] = 0;
  __syncthreads();
  for (int p = p0 + t; p < p1; p += 1024) {
    int d = (int)(ebuf[p] >> 17);
    atomicAdd(&hist[d], 1);
  }
  __syncthreads();
  // exclusive scan of hist[0..1024): per-wave shfl scan + wave-total scan
  int h = hist[t];
  int v = h;
#pragma unroll
  for (int o = 1; o < 64; o <<= 1) {
    int u = __shfl_up(v, o);
    if ((t & 63) >= o) v += u;
  }
  if ((t & 63) == 63) wsum[t >> 6] = v;
  __syncthreads();
  if (t < 64) {
    int w = (t < 16) ? wsum[t] : 0;
#pragma unroll
    for (int o = 1; o < 16; o <<= 1) {
      int u = __shfl_up(w, o);
      if (t >= o) w += u;
    }
    if (t < 16) wsum[t] = w;
  }
  __syncthreads();
  int base = (t >> 6) ? wsum[(t >> 6) - 1] : 0;
  int gpos = p0 + base + v - h;  // exclusive prefix
  int node = (b << BSHIFT) + t;
  if (node < N_NODES) off[node] = gpos;
  cur[t] = gpos;
  __syncthreads();
  for (int p = p0 + t; p < p1; p += 1024) {
    unsigned e = ebuf[p];
    int pos = atomicAdd(&cur[(int)(e >> 17)], 1);
    srcs[pos] = (int)(e & 0x1FFFFu);
  }
}

// fp32 -> fp16 copy (RN), 8 elems/thread, row-major
__global__ __launch_bounds__(256) void k_tohalf(const float* __restrict__ in, _Float16* __restrict__ o) {
  int i = blockIdx.x * 256 + threadIdx.x;
  if (i >= N_NODES * F / 8) return;
  float4 a = reinterpret_cast<const float4*>(in)[2 * i];
  float4 b = reinterpret_cast<const float4*>(in)[2 * i + 1];
  union {
    _Float16 h[8];
    uint4 u;
  } r;
  r.h[0] = (_Float16)a.x; r.h[1] = (_Float16)a.y; r.h[2] = (_Float16)a.z; r.h[3] = (_Float16)a.w;
  r.h[4] = (_Float16)b.x; r.h[5] = (_Float16)b.y; r.h[6] = (_Float16)b.z; r.h[7] = (_Float16)b.w;
  reinterpret_cast<uint4*>(o)[i] = r.u;
}

// one wave per node, fp16 row gather; lane l owns features [2l, 2l+1]; fp32 accumulate.
// src indices batch-loaded 64-at-a-time (one coalesced load) and broadcast via readlane.
// (Measured 59.7us, fetch-path-bound at ~3.8 TB/s; R8 proved fusion kills its TLP.)
__global__ __launch_bounds__(256) void k_aggregate(const _Float16* __restrict__ x, const int* __restrict__ off,
                                                   const int* __restrict__ srcs, float* __restrict__ agg) {
  int n = blockIdx.x * 4 + (threadIdx.x >> 6);
  if (n >= N_NODES) return;
  int l = threadIdx.x & 63;
  int p0 = off[n], p1 = off[n + 1];
  int deg = p1 - p0;
  float sx = 0.f, sy = 0.f;

  for (int base = 0; base < deg; base += 64) {
    int rem = deg - base;
    int cnt = (rem < 64) ? rem : 64;
    int my = (l < cnt) ? srcs[p0 + base + l] : 0;
    int j = 0;
    for (; j + 7 < cnt; j += 8) {
      int s[8];
#pragma unroll
      for (int k = 0; k < 8; ++k) s[k] = __builtin_amdgcn_readlane(my, j + k);
      f16x2 v[8];
#pragma unroll
      for (int k = 0; k < 8; ++k)
        v[k] = *reinterpret_cast<const f16x2*>(x + (size_t)(unsigned)s[k] * F + 2 * l);
#pragma unroll
      for (int k = 0; k < 8; ++k) {
        sx += (float)v[k][0];
        sy += (float)v[k][1];
      }
    }
    for (; j + 3 < cnt; j += 4) {
      int s[4];
#pragma unroll
      for (int k = 0; k < 4; ++k) s[k] = __builtin_amdgcn_readlane(my, j + k);
      f16x2 v[4];
#pragma unroll
      for (int k = 0; k < 4; ++k)
        v[k] = *reinterpret_cast<const f16x2*>(x + (size_t)(unsigned)s[k] * F + 2 * l);
#pragma unroll
      for (int k = 0; k < 4; ++k) {
        sx += (float)v[k][0];
        sy += (float)v[k][1];
      }
    }
    for (; j < cnt; ++j) {
      int s = __builtin_amdgcn_readlane(my, j);
      f16x2 v = *reinterpret_cast<const f16x2*>(x + (size_t)(unsigned)s * F + 2 * l);
      sx += (float)v[0];
      sy += (float)v[1];
    }
  }

  float inv = 1.0f / (float)max(deg, 1);
  float2 r;
  r.x = sx * inv;
  r.y = sy * inv;
  *reinterpret_cast<float2*>(agg + (size_t)n * F + 2 * l) = r;
}

// ---- split fp32 -> bf16 hi/lo (truncation; lo compensates, net rel err ~3*2^-16) ----
__device__ __forceinline__ void split_pack(const float4& a, const float4& b, bf16x8& hi, bf16x8& lo) {
  float f[8] = {a.x, a.y, a.z, a.w, b.x, b.y, b.z, b.w};
#pragma unroll
  for (int i = 0; i < 8; ++i) {
    union { float f; unsigned u; } u0;
    u0.f = f[i];
    hi[i] = (short)(u0.u >> 16);
    union { unsigned u; float f; } uh;
    uh.u = u0.u & 0xFFFF0000u;
    union { float f; unsigned u; } ur;
    ur.f = f[i] - uh.f;
    lo[i] = (short)(ur.u >> 16);
  }
}

// fp16 -> bf16 hi/lo split (EXACT: fp16 has 11 significand bits, hi takes 8, lo the rest)
__device__ __forceinline__ void split_pack_h(const f16x8& v, bf16x8& hi, bf16x8& lo) {
#pragma unroll
  for (int i = 0; i < 8; ++i) {
    float f = (float)v[i];
    union { float f; unsigned u; } u0;
    u0.f = f;
    hi[i] = (short)(u0.u >> 16);
    union { unsigned u; float f; } uh;
    uh.u = u0.u & 0xFFFF0000u;
    union { float f; unsigned u; } ur;
    ur.f = f - uh.f;
    lo[i] = (short)(ur.u >> 16);
  }
}

// pre-split weights: Wl/Wr per layer -> wsp[layer][4][128*128] bf16 (WlH, WlL, WrH, WrL)
__global__ __launch_bounds__(256) void k_wsplit(const float* __restrict__ Wl1, const float* __restrict__ Wr1,
                                                const float* __restrict__ Wl2, const float* __restrict__ Wr2,
                                                const float* __restrict__ Wl3, const float* __restrict__ Wr3,
                                                unsigned short* __restrict__ wsp) {
  int e = blockIdx.x * 256 + threadIdx.x;  // 0..49151
  if (e >= 3 * 16384) return;
  int L = e >> 14, off = e & 16383;
  const float* wl = (L == 0) ? Wl1 : (L == 1) ? Wl2 : Wl3;
  const float* wr = (L == 0) ? Wr1 : (L == 1) ? Wr2 : Wr3;
  unsigned short* base = wsp + (size_t)L * 4 * 16384;
  {
    union { float f; unsigned u; } u0;
    u0.f = wl[off];
    union { unsigned u; float f; } uh;
    uh.u = u0.u & 0xFFFF0000u;
    union { float f; unsigned u; } ur;
    ur.f = u0.f - uh.f;
    base[off] = (unsigned short)(u0.u >> 16);
    base[16384 + off] = (unsigned short)(ur.u >> 16);
  }
  {
    union { float f; unsigned u; } u0;
    u0.f = wr[off];
    union { unsigned u; float f; } uh;
    uh.u = u0.u & 0xFFFF0000u;
    union { float f; unsigned u; } ur;
    ur.f = u0.f - uh.f;
    base[2 * 16384 + off] = (unsigned short)(u0.u >> 16);
    base[3 * 16384 + off] = (unsigned short)(ur.u >> 16);
  }
}

// out[n][j] = normalize(dot(agg[n],Wl[j]) + dot(x[n],Wr[j]) + bl[j]) [+relu], split-bf16 MFMA.
// x read from the fp16 copy (16B/lane loads; fp16->bf16 hi/lo is exact) -> fp32 x reads and
// intermediate fp32 out writes eliminated (~177MB across the 3 layers). out fp32 nullable.
__global__ __launch_bounds__(832, 1) void k_linear(const float* __restrict__ agg, const _Float16* __restrict__ x16,
                                                   const unsigned short* __restrict__ wsp,  // [4][128][128]
                                                   const float* __restrict__ bl, float* __restrict__ out,
                                                   _Float16* __restrict__ out16, int relu) {
  __shared__ unsigned short wlds[4][128][136];  // +8 pad: b128 frag reads ~2-way max
  int tid = threadIdx.x;

  for (int c = tid; c < 4 * 2048; c += 832) {
    int m = c >> 11, rem = c & 2047;
    int j = rem >> 4, kc = (rem & 15) * 8;
    uint4 v = *reinterpret_cast<const uint4*>(wsp + (size_t)m * 16384 + j * 128 + kc);
    *reinterpret_cast<uint4*>(&wlds[m][j][kc]) = v;
  }
  __syncthreads();

  int wid = tid >> 6, lane = tid & 63;
  int l31 = lane & 31, lhi = lane >> 5;
  long rb = (long)blockIdx.x * LBM + (long)wid * 32;
  if (rb >= N_NODES) return;  // whole-wave out of range (after barrier)

  int r0 = (int)min(rb + l31, (long)N_NODES - 1);
  const float* a0p = agg + (size_t)r0 * F + lhi * 8;
  const _Float16* x0p = x16 + (size_t)r0 * F + lhi * 8;

  f32x16 acc[4];
#pragma unroll
  for (int ct = 0; ct < 4; ++ct) acc[ct] = (f32x16)0.f;

  float4 ap = *reinterpret_cast<const float4*>(a0p);
  float4 aq = *reinterpret_cast<const float4*>(a0p + 4);
  f16x8 xv = *reinterpret_cast<const f16x8*>(x0p);

#pragma unroll
  for (int ks = 0; ks < 8; ++ks) {
    float4 ap_n, aq_n;
    f16x8 xv_n;
    if (ks < 7) {
      const float* an = a0p + (ks + 1) * 16;
      ap_n = *reinterpret_cast<const float4*>(an);
      aq_n = *reinterpret_cast<const float4*>(an + 4);
      xv_n = *reinterpret_cast<const f16x8*>(x0p + (ks + 1) * 16);
    }
    int k0 = ks * 16 + lhi * 8;
    bf16x8 aH0, aL0, xH0, xL0;
    split_pack(ap, aq, aH0, aL0);
    split_pack_h(xv, xH0, xL0);
#pragma unroll
    for (int ct = 0; ct < 4; ++ct) {
      int j = ct * 32 + l31;
      bf16x8 BlH = *reinterpret_cast<const bf16x8*>(&wlds[0][j][k0]);
      bf16x8 BlL = *reinterpret_cast<const bf16x8*>(&wlds[1][j][k0]);
      bf16x8 BrH = *reinterpret_cast<const bf16x8*>(&wlds[2][j][k0]);
      bf16x8 BrL = *reinterpret_cast<const bf16x8*>(&wlds[3][j][k0]);
      acc[ct] = __builtin_amdgcn_mfma_f32_32x32x16_bf16(aH0, BlH, acc[ct], 0, 0, 0);
      acc[ct] = __builtin_amdgcn_mfma_f32_32x32x16_bf16(aL0, BlH, acc[ct], 0, 0, 0);
      acc[ct] = __builtin_amdgcn_mfma_f32_32x32x16_bf16(aH0, BlL, acc[ct], 0, 0, 0);
      acc[ct] = __builtin_amdgcn_mfma_f32_32x32x16_bf16(xH0, BrH, acc[ct], 0, 0, 0);
      acc[ct] = __builtin_amdgcn_mfma_f32_32x32x16_bf16(xL0, BrH, acc[ct], 0, 0, 0);
      acc[ct] = __builtin_amdgcn_mfma_f32_32x32x16_bf16(xH0, BrL, acc[ct], 0, 0, 0);
    }
    ap = ap_n;
    aq = aq_n;
    xv = xv_n;
  }

  // epilogue: +bias, row L2-norm across 32 lanes (same lhi), optional relu, masked store.
#pragma unroll
  for (int ct = 0; ct < 4; ++ct) {
    float b = bl[ct * 32 + l31];
#pragma unroll
    for (int i = 0; i < 16; ++i) acc[ct][i] += b;
  }
#pragma unroll
  for (int i = 0; i < 16; ++i) {
    float ss = acc[0][i] * acc[0][i] + acc[1][i] * acc[1][i] +
               acc[2][i] * acc[2][i] + acc[3][i] * acc[3][i];
#pragma unroll
    for (int o = 1; o < 32; o <<= 1) ss += __shfl_xor(ss, o);
    float inv = 1.0f / fmaxf(sqrtf(ss), 1e-12f);
    long grow = rb + (i & 3) + 8 * (i >> 2) + 4 * lhi;
    if (grow < N_NODES) {
      long base = grow * F + l31;
#pragma unroll
      for (int ct = 0; ct < 4; ++ct) {
        float v = acc[ct][i] * inv;
        if (relu) v = fmaxf(v, 0.f);
        if (out) out[base + ct * 32] = v;
        if (out16) out16[base + ct * 32] = (_Float16)v;
      }
    }
  }
}

// 32 nodes/block (grid = N_NODES/32 = 3125); Wfc + h tile in LDS; 8 threads/node x 5 classes
#define FCP 132
__global__ __launch_bounds__(256) void k_fc_softmax(const float* __restrict__ h, const float* __restrict__ Wfc,
                                                    const float* __restrict__ bfc, float* __restrict__ out) {
  __shared__ float w_s[OUT_CLS][FCP];
  __shared__ float h_s[32][FCP];
  int tid = threadIdx.x;
  int nb = blockIdx.x * 32;

  for (int i = tid; i < OUT_CLS * (F / 4); i += 256) {
    int r = i >> 5, c = (i & 31) * 4;
    *reinterpret_cast<float4*>(&w_s[r][c]) = *reinterpret_cast<const float4*>(Wfc + (size_t)r * F + c);
  }
  for (int i = tid; i < 32 * (F / 4); i += 256) {
    int r = i >> 5, c = (i & 31) * 4;
    *reinterpret_cast<float4*>(&h_s[r][c]) = *reinterpret_cast<const float4*>(h + (size_t)(nb + r) * F + c);
  }
  __syncthreads();

  int r = tid >> 3, sub = tid & 7;
  float acc[5];
#pragma unroll
  for (int c = 0; c < 5; ++c) acc[c] = bfc[sub * 5 + c];

  for (int k4 = 0; k4 < F / 4; ++k4) {
    float4 hv = *reinterpret_cast<const float4*>(&h_s[r][k4 * 4]);
#pragma unroll
    for (int c = 0; c < 5; ++c) {
      float4 wv = *reinterpret_cast<const float4*>(&w_s[sub * 5 + c][k4 * 4]);
      acc[c] += hv.x * wv.x + hv.y * wv.y + hv.z * wv.z + hv.w * wv.w;
    }
  }

  float m = acc[0];
#pragma unroll
  for (int c = 1; c < 5; ++c) m = fmaxf(m, acc[c]);
#pragma unroll
  for (int o = 4; o > 0; o >>= 1) m = fmaxf(m, __shfl_xor(m, o));
  float e[5], s = 0.f;
#pragma unroll
  for (int c = 0; c < 5; ++c) {
    e[c] = expf(acc[c] - m);
    s += e[c];
  }
#pragma unroll
  for (int o = 4; o > 0; o >>= 1) s += __shfl_xor(s, o);
  float inv = 1.0f / s;
#pragma unroll
  for (int c = 0; c < 5; ++c) out[(size_t)(nb + r) * OUT_CLS + sub * 5 + c] = e[c] * inv;
}

extern "C" void kernel_launch(void* const* d_in, const int* in_sizes, int n_in, void* d_out, int out_size,
                              void* d_ws, size_t ws_size, hipStream_t stream) {
  const float* feat = (const float*)d_in[0];
  const int* eb = (const int*)d_in[1];
  const float* Wl1 = (const float*)d_in[2];
  const float* bl1 = (const float*)d_in[3];
  const float* Wr1 = (const float*)d_in[4];
  const float* Wl2 = (const float*)d_in[5];
  const float* bl2 = (const float*)d_in[6];
  const float* Wr2 = (const float*)d_in[7];
  const float* Wl3 = (const float*)d_in[8];
  const float* bl3 = (const float*)d_in[9];
  const float* Wr3 = (const float*)d_in[10];
  const float* Wfc = (const float*)d_in[11];
  const float* bfc = (const float*)d_in[12];
  float* out = (float*)d_out;

  char* w = (char*)d_ws;
  auto alloc = [&](size_t bytes) {
    char* p = w;
    w += (bytes + 255) & ~(size_t)255;
    return p;
  };
  int* flag = (int*)alloc(4);
  int* bhist = (int*)alloc((size_t)NBUCK * 4);
  int* boff = (int*)alloc((size_t)(NBUCK + 1) * 4);
  int* off = (int*)alloc((size_t)(N_NODES + 1) * 4);
  int* srcs = (int*)alloc((size_t)N_EDGES * 4 + 256);  // +pad
  int* bkt_cursor = (int*)alloc((size_t)NBUCK * 4);
  unsigned short* wsp = (unsigned short*)alloc((size_t)3 * 4 * 16384 * 2);
  float* bufA = (float*)alloc((size_t)N_NODES * F * 4);
  float* bufB = (float*)alloc((size_t)N_NODES * F * 4);
  _Float16* h16X = (_Float16*)alloc((size_t)N_NODES * F * 2);  // feat16, later h2_16
  _Float16* h16A = (_Float16*)alloc((size_t)N_NODES * F * 2);  // h1_16
  unsigned* ebuf = (unsigned*)bufB;  // dead before bufB's first use (layer-2 aggregate)
  (void)ws_size;
  (void)in_sizes;
  (void)n_in;
  (void)out_size;

  hipMemsetAsync(bhist, 0, (size_t)NBUCK * 4, stream);
  k_detect<<<1, 64, 0, stream>>>((const unsigned int*)eb, flag);
  k_chist<<<(N_EDGES + 256 * CH_E - 1) / (256 * CH_E), 256, 0, stream>>>(eb, flag, bhist);
  k_bscan<<<1, 128, 0, stream>>>(bhist, boff, bkt_cursor, off);
  k_bscatter<<<(N_EDGES + TILE - 1) / TILE, 256, 0, stream>>>(eb, flag, bkt_cursor, ebuf);
  k_fsort<<<NBUCK, 1024, 0, stream>>>(ebuf, boff, off, srcs);
  k_wsplit<<<192, 256, 0, stream>>>(Wl1, Wr1, Wl2, Wr2, Wl3, Wr3, wsp);
  k_tohalf<<<(N_NODES * F / 8 + 255) / 256, 256, 0, stream>>>(feat, h16X);

  const int nag = (N_NODES + 3) / 4;           // one wave per node
  const int nlin = (N_NODES + LBM - 1) / LBM;  // 241 (single round on 256 CUs)
  const int nfc = N_NODES / 32;                // 3125

  // layer 1: gather h16X(feat16) -> bufA agg; linear(agg=bufA, x16=h16X) -> h16A only
  k_aggregate<<<nag, 256, 0, stream>>>(h16X, off, srcs, bufA);
  k_linear<<<nlin, 832, 0, stream>>>(bufA, h16X, wsp + 0 * 4 * 16384, bl1, ((float*)0), h16A, 1);
  // layer 2: gather h16A -> bufB agg; linear(agg=bufB, x16=h16A) -> h16X only (h2_16)
  k_aggregate<<<nag, 256, 0, stream>>>(h16A, off, srcs, bufB);
  k_linear<<<nlin, 832, 0, stream>>>(bufB, h16A, wsp + 1 * 4 * 16384, bl2, ((float*)0), h16X, 1);
  // layer 3: gather h16X -> bufA agg; linear(agg=bufA, x16=h16X) -> bufB fp32 (for FC)
  k_aggregate<<<nag, 256, 0, stream>>>(h16X, off, srcs, bufA);
  k_linear<<<nlin, 832, 0, stream>>>(bufA, h16X, wsp + 2 * 4 * 16384, bl3, bufB, ((_Float16*)0), 0);
  // FC + softmax
  k_fc_softmax<<<nfc, 256, 0, stream>>>(bufB, Wfc, bfc, out);
}

// Round 10
// 369.198 us; speedup vs baseline: 2.0758x; 1.0715x over previous
//
#include <hip/hip_runtime.h>
#include <cstdint>

#define N_NODES 100000
#define N_EDGES 1600000
#define F 128
#define OUT_CLS 40
#define LW 13          // waves per k_linear block
#define LBM (LW * 32)  // 416 rows per block -> grid 241 <= 256 CUs (single round)
#define BSHIFT 10      // coarse bucket = dst >> 10 (1024 nodes)
#define NBUCK 98       // ceil(100000/1024)
#define TILE 2048      // edges per k_bscatter block
#define ECAP 24576     // per-bucket ebuf segment capacity (mean 16384, sd~127 -> +64 sigma)

using f32x16 = __attribute__((ext_vector_type(16))) float;
using bf16x8 = __attribute__((ext_vector_type(8))) short;
using f16x2 = __attribute__((ext_vector_type(2))) _Float16;
using f16x8 = __attribute__((ext_vector_type(8))) _Float16;

// ---- edge accessor: flag=1 means int64 storage (little-endian low word at 2*idx) ----
__device__ __forceinline__ int edge_val(const int* eb, int is64, long idx) {
  return is64 ? eb[2 * idx] : eb[idx];
}

__global__ void k_detect(const unsigned int* eb, int* flag) {
  if (threadIdx.x == 0 && blockIdx.x == 0) {
    int is64 = 1;
#pragma unroll
    for (int i = 1; i < 16; i += 2) is64 &= (eb[i] == 0u);
    flag[0] = is64;
  }
}

// coarse scatter (single pass, no pre-histogram): LDS counting-sort a 2048-edge tile by
// bucket, reserve per-bucket runs in fixed-stride segments ebuf[b*ECAP ...] via one global
// atomic/bucket/tile, copy out coalesced. ebuf entry packed: src | (dst&1023)<<17.
// bkt_cursor starts at 0 and ends as the per-bucket edge count.
__global__ __launch_bounds__(256) void k_bscatter(const int* __restrict__ eb, const int* __restrict__ flag,
                                                  int* __restrict__ bkt_cursor, unsigned* __restrict__ ebuf) {
  __shared__ int lhist[128];
  __shared__ int lbase[128];
  __shared__ int gbase[NBUCK];
  __shared__ int lcnt[NBUCK];
  __shared__ unsigned buf[TILE];
  __shared__ int slotpos[TILE];
  int t = threadIdx.x;
  long e0 = (long)blockIdx.x * TILE;
  int is64 = flag[0];
  if (t < 128) lhist[t] = 0;
  __syncthreads();
#pragma unroll
  for (int i = 0; i < TILE / 256; ++i) {
    long e = e0 + t + i * 256;
    if (e < N_EDGES) {
      int d = edge_val(eb, is64, (long)N_EDGES + e);
      atomicAdd(&lhist[d >> BSHIFT], 1);
    }
  }
  __syncthreads();
  if (t < 128) lbase[t] = lhist[t];
  __syncthreads();
  for (int d = 1; d < 128; d <<= 1) {
    int v = (t >= d && t < 128) ? lbase[t - d] : 0;
    __syncthreads();
    if (t < 128) lbase[t] += v;
    __syncthreads();
  }
  if (t < NBUCK) {
    gbase[t] = atomicAdd(&bkt_cursor[t], lhist[t]);
    lcnt[t] = 0;
  }
  __syncthreads();
#pragma unroll
  for (int i = 0; i < TILE / 256; ++i) {
    long e = e0 + t + i * 256;
    if (e < N_EDGES) {
      int d = edge_val(eb, is64, (long)N_EDGES + e);
      int s = edge_val(eb, is64, e);
      int b = d >> BSHIFT;
      int n = atomicAdd(&lcnt[b], 1);
      int slot = lbase[b] - lhist[b] + n;
      buf[slot] = (unsigned)s | ((unsigned)(d & 1023) << 17);
      slotpos[slot] = b * ECAP + gbase[b] + n;
    }
  }
  __syncthreads();
  int tile_n = (int)min((long)TILE, (long)N_EDGES - e0);
  for (int i = t; i < tile_n; i += 256) {
    ebuf[slotpos[i]] = buf[i];
  }
}

// scan the 98 bucket counts (= bkt_cursor after bscatter) -> boff[0..98]; off[N]=N_EDGES
__global__ __launch_bounds__(128) void k_bscan2(const int* __restrict__ bkt_cursor, int* __restrict__ boff,
                                                int* __restrict__ off) {
  __shared__ int sh[128];
  int t = threadIdx.x;
  int v = (t < NBUCK) ? bkt_cursor[t] : 0;
  sh[t] = v;
  __syncthreads();
  for (int d = 1; d < 128; d <<= 1) {
    int u = (t >= d) ? sh[t - d] : 0;
    __syncthreads();
    sh[t] += u;
    __syncthreads();
  }
  int incl = sh[t];
  if (t < NBUCK) boff[t] = incl - v;
  if (t == NBUCK - 1) boff[NBUCK] = incl;
  if (t == 0) off[N_NODES] = N_EDGES;
}

// per-bucket fine sort: LDS 1024-bin histogram + wave-shuffle scan -> off[node], then
// LDS-cursor scatter of srcs. Reads the fixed-stride segment ebuf[b*ECAP ...].
__global__ __launch_bounds__(1024) void k_fsort(const unsigned* __restrict__ ebuf, const int* __restrict__ boff,
                                                int* __restrict__ off, int* __restrict__ srcs) {
  __shared__ int hist[1024];
  __shared__ int cur[1024];
  __shared__ int wsum[16];
  int b = blockIdx.x;
  int t = threadIdx.x;
  int p0 = boff[b], p1 = boff[b + 1];
  int cnt = p1 - p0;
  const unsigned* seg = ebuf + (size_t)b * ECAP;
  hist[t] = 0;
  __syncthreads();
  for (int p = t; p < cnt; p += 1024) {
    int d = (int)(seg[p] >> 17);
    atomicAdd(&hist[d], 1);
  }
  __syncthreads();
  // exclusive scan of hist[0..1024): per-wave shfl scan + wave-total scan
  int h = hist[t];
  int v = h;
#pragma unroll
  for (int o = 1; o < 64; o <<= 1) {
    int u = __shfl_up(v, o);
    if ((t & 63) >= o) v += u;
  }
  if ((t & 63) == 63) wsum[t >> 6] = v;
  __syncthreads();
  if (t < 64) {
    int w = (t < 16) ? wsum[t] : 0;
#pragma unroll
    for (int o = 1; o < 16; o <<= 1) {
      int u = __shfl_up(w, o);
      if (t >= o) w += u;
    }
    if (t < 16) wsum[t] = w;
  }
  __syncthreads();
  int base = (t >> 6) ? wsum[(t >> 6) - 1] : 0;
  int gpos = p0 + base + v - h;  // exclusive prefix
  int node = (b << BSHIFT) + t;
  if (node < N_NODES) off[node] = gpos;
  cur[t] = gpos;
  __syncthreads();
  for (int p = t; p < cnt; p += 1024) {
    unsigned e = seg[p];
    int pos = atomicAdd(&cur[(int)(e >> 17)], 1);
    srcs[pos] = (int)(e & 0x1FFFFu);
  }
}

// fp32 -> fp16 copy (RN), 8 elems/thread, row-major
__global__ __launch_bounds__(256) void k_tohalf(const float* __restrict__ in, _Float16* __restrict__ o) {
  int i = blockIdx.x * 256 + threadIdx.x;
  if (i >= N_NODES * F / 8) return;
  float4 a = reinterpret_cast<const float4*>(in)[2 * i];
  float4 b = reinterpret_cast<const float4*>(in)[2 * i + 1];
  union {
    _Float16 h[8];
    uint4 u;
  } r;
  r.h[0] = (_Float16)a.x; r.h[1] = (_Float16)a.y; r.h[2] = (_Float16)a.z; r.h[3] = (_Float16)a.w;
  r.h[4] = (_Float16)b.x; r.h[5] = (_Float16)b.y; r.h[6] = (_Float16)b.z; r.h[7] = (_Float16)b.w;
  reinterpret_cast<uint4*>(o)[i] = r.u;
}

// one wave per node, fp16 row gather; lane l owns features [2l, 2l+1]; fp32 accumulate,
// fp16 mean output (halves agg write traffic; consumers split fp16 exactly).
// (Fetch-path-bound at ~3.9 TB/s; R4 MLP-doubling null, R8 fusion kills TLP.)
__global__ __launch_bounds__(256) void k_aggregate(const _Float16* __restrict__ x, const int* __restrict__ off,
                                                   const int* __restrict__ srcs, _Float16* __restrict__ agg16) {
  int n = blockIdx.x * 4 + (threadIdx.x >> 6);
  if (n >= N_NODES) return;
  int l = threadIdx.x & 63;
  int p0 = off[n], p1 = off[n + 1];
  int deg = p1 - p0;
  float sx = 0.f, sy = 0.f;

  for (int base = 0; base < deg; base += 64) {
    int rem = deg - base;
    int cnt = (rem < 64) ? rem : 64;
    int my = (l < cnt) ? srcs[p0 + base + l] : 0;
    int j = 0;
    for (; j + 7 < cnt; j += 8) {
      int s[8];
#pragma unroll
      for (int k = 0; k < 8; ++k) s[k] = __builtin_amdgcn_readlane(my, j + k);
      f16x2 v[8];
#pragma unroll
      for (int k = 0; k < 8; ++k)
        v[k] = *reinterpret_cast<const f16x2*>(x + (size_t)(unsigned)s[k] * F + 2 * l);
#pragma unroll
      for (int k = 0; k < 8; ++k) {
        sx += (float)v[k][0];
        sy += (float)v[k][1];
      }
    }
    for (; j + 3 < cnt; j += 4) {
      int s[4];
#pragma unroll
      for (int k = 0; k < 4; ++k) s[k] = __builtin_amdgcn_readlane(my, j + k);
      f16x2 v[4];
#pragma unroll
      for (int k = 0; k < 4; ++k)
        v[k] = *reinterpret_cast<const f16x2*>(x + (size_t)(unsigned)s[k] * F + 2 * l);
#pragma unroll
      for (int k = 0; k < 4; ++k) {
        sx += (float)v[k][0];
        sy += (float)v[k][1];
      }
    }
    for (; j < cnt; ++j) {
      int s = __builtin_amdgcn_readlane(my, j);
      f16x2 v = *reinterpret_cast<const f16x2*>(x + (size_t)(unsigned)s * F + 2 * l);
      sx += (float)v[0];
      sy += (float)v[1];
    }
  }

  float inv = 1.0f / (float)max(deg, 1);
  f16x2 r;
  r[0] = (_Float16)(sx * inv);
  r[1] = (_Float16)(sy * inv);
  *reinterpret_cast<f16x2*>(agg16 + (size_t)n * F + 2 * l) = r;
}

// fp16 -> bf16 hi/lo split (EXACT: fp16 has 11 significand bits, hi takes 8, lo the rest)
__device__ __forceinline__ void split_pack_h(const f16x8& v, bf16x8& hi, bf16x8& lo) {
#pragma unroll
  for (int i = 0; i < 8; ++i) {
    float f = (float)v[i];
    union { float f; unsigned u; } u0;
    u0.f = f;
    hi[i] = (short)(u0.u >> 16);
    union { unsigned u; float f; } uh;
    uh.u = u0.u & 0xFFFF0000u;
    union { float f; unsigned u; } ur;
    ur.f = f - uh.f;
    lo[i] = (short)(ur.u >> 16);
  }
}

// pre-split weights: Wl/Wr per layer -> wsp[layer][4][128*128] bf16 (WlH, WlL, WrH, WrL)
__global__ __launch_bounds__(256) void k_wsplit(const float* __restrict__ Wl1, const float* __restrict__ Wr1,
                                                const float* __restrict__ Wl2, const float* __restrict__ Wr2,
                                                const float* __restrict__ Wl3, const float* __restrict__ Wr3,
                                                unsigned short* __restrict__ wsp) {
  int e = blockIdx.x * 256 + threadIdx.x;  // 0..49151
  if (e >= 3 * 16384) return;
  int L = e >> 14, off = e & 16383;
  const float* wl = (L == 0) ? Wl1 : (L == 1) ? Wl2 : Wl3;
  const float* wr = (L == 0) ? Wr1 : (L == 1) ? Wr2 : Wr3;
  unsigned short* base = wsp + (size_t)L * 4 * 16384;
  {
    union { float f; unsigned u; } u0;
    u0.f = wl[off];
    union { unsigned u; float f; } uh;
    uh.u = u0.u & 0xFFFF0000u;
    union { float f; unsigned u; } ur;
    ur.f = u0.f - uh.f;
    base[off] = (unsigned short)(u0.u >> 16);
    base[16384 + off] = (unsigned short)(ur.u >> 16);
  }
  {
    union { float f; unsigned u; } u0;
    u0.f = wr[off];
    union { unsigned u; float f; } uh;
    uh.u = u0.u & 0xFFFF0000u;
    union { float f; unsigned u; } ur;
    ur.f = u0.f - uh.f;
    base[2 * 16384 + off] = (unsigned short)(u0.u >> 16);
    base[3 * 16384 + off] = (unsigned short)(ur.u >> 16);
  }
}

// out[n][j] = normalize(dot(agg[n],Wl[j]) + dot(x[n],Wr[j]) + bl[j]) [+relu], split-bf16 MFMA.
// Both operands fp16 (16B/lane loads, exact bf16 hi/lo split). out fp32 / out16 nullable.
__global__ __launch_bounds__(832, 1) void k_linear(const _Float16* __restrict__ agg16,
                                                   const _Float16* __restrict__ x16,
                                                   const unsigned short* __restrict__ wsp,  // [4][128][128]
                                                   const float* __restrict__ bl, float* __restrict__ out,
                                                   _Float16* __restrict__ out16, int relu) {
  __shared__ unsigned short wlds[4][128][136];  // +8 pad: b128 frag reads ~2-way max
  int tid = threadIdx.x;

  for (int c = tid; c < 4 * 2048; c += 832) {
    int m = c >> 11, rem = c & 2047;
    int j = rem >> 4, kc = (rem & 15) * 8;
    uint4 v = *reinterpret_cast<const uint4*>(wsp + (size_t)m * 16384 + j * 128 + kc);
    *reinterpret_cast<uint4*>(&wlds[m][j][kc]) = v;
  }
  __syncthreads();

  int wid = tid >> 6, lane = tid & 63;
  int l31 = lane & 31, lhi = lane >> 5;
  long rb = (long)blockIdx.x * LBM + (long)wid * 32;
  if (rb >= N_NODES) return;  // whole-wave out of range (after barrier)

  int r0 = (int)min(rb + l31, (long)N_NODES - 1);
  const _Float16* a0p = agg16 + (size_t)r0 * F + lhi * 8;
  const _Float16* x0p = x16 + (size_t)r0 * F + lhi * 8;

  f32x16 acc[4];
#pragma unroll
  for (int ct = 0; ct < 4; ++ct) acc[ct] = (f32x16)0.f;

  f16x8 av = *reinterpret_cast<const f16x8*>(a0p);
  f16x8 xv = *reinterpret_cast<const f16x8*>(x0p);

#pragma unroll
  for (int ks = 0; ks < 8; ++ks) {
    f16x8 av_n, xv_n;
    if (ks < 7) {
      av_n = *reinterpret_cast<const f16x8*>(a0p + (ks + 1) * 16);
      xv_n = *reinterpret_cast<const f16x8*>(x0p + (ks + 1) * 16);
    }
    int k0 = ks * 16 + lhi * 8;
    bf16x8 aH0, aL0, xH0, xL0;
    split_pack_h(av, aH0, aL0);
    split_pack_h(xv, xH0, xL0);
#pragma unroll
    for (int ct = 0; ct < 4; ++ct) {
      int j = ct * 32 + l31;
      bf16x8 BlH = *reinterpret_cast<const bf16x8*>(&wlds[0][j][k0]);
      bf16x8 BlL = *reinterpret_cast<const bf16x8*>(&wlds[1][j][k0]);
      bf16x8 BrH = *reinterpret_cast<const bf16x8*>(&wlds[2][j][k0]);
      bf16x8 BrL = *reinterpret_cast<const bf16x8*>(&wlds[3][j][k0]);
      acc[ct] = __builtin_amdgcn_mfma_f32_32x32x16_bf16(aH0, BlH, acc[ct], 0, 0, 0);
      acc[ct] = __builtin_amdgcn_mfma_f32_32x32x16_bf16(aL0, BlH, acc[ct], 0, 0, 0);
      acc[ct] = __builtin_amdgcn_mfma_f32_32x32x16_bf16(aH0, BlL, acc[ct], 0, 0, 0);
      acc[ct] = __builtin_amdgcn_mfma_f32_32x32x16_bf16(xH0, BrH, acc[ct], 0, 0, 0);
      acc[ct] = __builtin_amdgcn_mfma_f32_32x32x16_bf16(xL0, BrH, acc[ct], 0, 0, 0);
      acc[ct] = __builtin_amdgcn_mfma_f32_32x32x16_bf16(xH0, BrL, acc[ct], 0, 0, 0);
    }
    av = av_n;
    xv = xv_n;
  }

  // epilogue: +bias, row L2-norm across 32 lanes (same lhi), optional relu, masked store.
#pragma unroll
  for (int ct = 0; ct < 4; ++ct) {
    float b = bl[ct * 32 + l31];
#pragma unroll
    for (int i = 0; i < 16; ++i) acc[ct][i] += b;
  }
#pragma unroll
  for (int i = 0; i < 16; ++i) {
    float ss = acc[0][i] * acc[0][i] + acc[1][i] * acc[1][i] +
               acc[2][i] * acc[2][i] + acc[3][i] * acc[3][i];
#pragma unroll
    for (int o = 1; o < 32; o <<= 1) ss += __shfl_xor(ss, o);
    float inv = 1.0f / fmaxf(sqrtf(ss), 1e-12f);
    long grow = rb + (i & 3) + 8 * (i >> 2) + 4 * lhi;
    if (grow < N_NODES) {
      long base = grow * F + l31;
#pragma unroll
      for (int ct = 0; ct < 4; ++ct) {
        float v = acc[ct][i] * inv;
        if (relu) v = fmaxf(v, 0.f);
        if (out) out[base + ct * 32] = v;
        if (out16) out16[base + ct * 32] = (_Float16)v;
      }
    }
  }
}

// 32 nodes/block (grid = N_NODES/32 = 3125); Wfc + h tile in LDS; 8 threads/node x 5 classes
#define FCP 132
__global__ __launch_bounds__(256) void k_fc_softmax(const float* __restrict__ h, const float* __restrict__ Wfc,
                                                    const float* __restrict__ bfc, float* __restrict__ out) {
  __shared__ float w_s[OUT_CLS][FCP];
  __shared__ float h_s[32][FCP];
  int tid = threadIdx.x;
  int nb = blockIdx.x * 32;

  for (int i = tid; i < OUT_CLS * (F / 4); i += 256) {
    int r = i >> 5, c = (i & 31) * 4;
    *reinterpret_cast<float4*>(&w_s[r][c]) = *reinterpret_cast<const float4*>(Wfc + (size_t)r * F + c);
  }
  for (int i = tid; i < 32 * (F / 4); i += 256) {
    int r = i >> 5, c = (i & 31) * 4;
    *reinterpret_cast<float4*>(&h_s[r][c]) = *reinterpret_cast<const float4*>(h + (size_t)(nb + r) * F + c);
  }
  __syncthreads();

  int r = tid >> 3, sub = tid & 7;
  float acc[5];
#pragma unroll
  for (int c = 0; c < 5; ++c) acc[c] = bfc[sub * 5 + c];

  for (int k4 = 0; k4 < F / 4; ++k4) {
    float4 hv = *reinterpret_cast<const float4*>(&h_s[r][k4 * 4]);
#pragma unroll
    for (int c = 0; c < 5; ++c) {
      float4 wv = *reinterpret_cast<const float4*>(&w_s[sub * 5 + c][k4 * 4]);
      acc[c] += hv.x * wv.x + hv.y * wv.y + hv.z * wv.z + hv.w * wv.w;
    }
  }

  float m = acc[0];
#pragma unroll
  for (int c = 1; c < 5; ++c) m = fmaxf(m, acc[c]);
#pragma unroll
  for (int o = 4; o > 0; o >>= 1) m = fmaxf(m, __shfl_xor(m, o));
  float e[5], s = 0.f;
#pragma unroll
  for (int c = 0; c < 5; ++c) {
    e[c] = expf(acc[c] - m);
    s += e[c];
  }
#pragma unroll
  for (int o = 4; o > 0; o >>= 1) s += __shfl_xor(s, o);
  float inv = 1.0f / s;
#pragma unroll
  for (int c = 0; c < 5; ++c) out[(size_t)(nb + r) * OUT_CLS + sub * 5 + c] = e[c] * inv;
}

extern "C" void kernel_launch(void* const* d_in, const int* in_sizes, int n_in, void* d_out, int out_size,
                              void* d_ws, size_t ws_size, hipStream_t stream) {
  const float* feat = (const float*)d_in[0];
  const int* eb = (const int*)d_in[1];
  const float* Wl1 = (const float*)d_in[2];
  const float* bl1 = (const float*)d_in[3];
  const float* Wr1 = (const float*)d_in[4];
  const float* Wl2 = (const float*)d_in[5];
  const float* bl2 = (const float*)d_in[6];
  const float* Wr2 = (const float*)d_in[7];
  const float* Wl3 = (const float*)d_in[8];
  const float* bl3 = (const float*)d_in[9];
  const float* Wr3 = (const float*)d_in[10];
  const float* Wfc = (const float*)d_in[11];
  const float* bfc = (const float*)d_in[12];
  float* out = (float*)d_out;

  char* w = (char*)d_ws;
  auto alloc = [&](size_t bytes) {
    char* p = w;
    w += (bytes + 255) & ~(size_t)255;
    return p;
  };
  int* flag = (int*)alloc(4);
  int* boff = (int*)alloc((size_t)(NBUCK + 1) * 4);
  int* off = (int*)alloc((size_t)(N_NODES + 1) * 4);
  int* srcs = (int*)alloc((size_t)N_EDGES * 4 + 256);  // +pad
  int* bkt_cursor = (int*)alloc((size_t)NBUCK * 4);
  unsigned short* wsp = (unsigned short*)alloc((size_t)3 * 4 * 16384 * 2);
  float* bufB = (float*)alloc((size_t)N_NODES * F * 4);        // layer-3 fp32 out (+ebuf alias)
  _Float16* agg16 = (_Float16*)alloc((size_t)N_NODES * F * 2); // gather output
  _Float16* h16X = (_Float16*)alloc((size_t)N_NODES * F * 2);  // feat16, later h2_16
  _Float16* h16A = (_Float16*)alloc((size_t)N_NODES * F * 2);  // h1_16
  unsigned* ebuf = (unsigned*)bufB;  // 98*ECAP*4 = 9.6MB, dead before bufB's first use
  (void)ws_size;
  (void)in_sizes;
  (void)n_in;
  (void)out_size;

  hipMemsetAsync(bkt_cursor, 0, (size_t)NBUCK * 4, stream);
  k_detect<<<1, 64, 0, stream>>>((const unsigned int*)eb, flag);
  k_bscatter<<<(N_EDGES + TILE - 1) / TILE, 256, 0, stream>>>(eb, flag, bkt_cursor, ebuf);
  k_bscan2<<<1, 128, 0, stream>>>(bkt_cursor, boff, off);
  k_fsort<<<NBUCK, 1024, 0, stream>>>(ebuf, boff, off, srcs);
  k_wsplit<<<192, 256, 0, stream>>>(Wl1, Wr1, Wl2, Wr2, Wl3, Wr3, wsp);
  k_tohalf<<<(N_NODES * F / 8 + 255) / 256, 256, 0, stream>>>(feat, h16X);

  const int nag = (N_NODES + 3) / 4;           // one wave per node
  const int nlin = (N_NODES + LBM - 1) / LBM;  // 241 (single round on 256 CUs)
  const int nfc = N_NODES / 32;                // 3125

  // layer 1: gather h16X(feat16) -> agg16; linear(agg16, x16=h16X) -> h16A only
  k_aggregate<<<nag, 256, 0, stream>>>(h16X, off, srcs, agg16);
  k_linear<<<nlin, 832, 0, stream>>>(agg16, h16X, wsp + 0 * 4 * 16384, bl1, ((float*)0), h16A, 1);
  // layer 2: gather h16A -> agg16; linear(agg16, x16=h16A) -> h16X only (h2_16)
  k_aggregate<<<nag, 256, 0, stream>>>(h16A, off, srcs, agg16);
  k_linear<<<nlin, 832, 0, stream>>>(agg16, h16A, wsp + 1 * 4 * 16384, bl2, ((float*)0), h16X, 1);
  // layer 3: gather h16X -> agg16; linear(agg16, x16=h16X) -> bufB fp32 (for FC)
  k_aggregate<<<nag, 256, 0, stream>>>(h16X, off, srcs, agg16);
  k_linear<<<nlin, 832, 0, stream>>>(agg16, h16X, wsp + 2 * 4 * 16384, bl3, bufB, ((_Float16*)0), 0);
  // FC + softmax
  k_fc_softmax<<<nfc, 256, 0, stream>>>(bufB, Wfc, bfc, out);
}

// Round 11
// 356.254 us; speedup vs baseline: 2.1513x; 1.0363x over previous
//
#include <hip/hip_runtime.h>
#include <cstdint>

#define N_NODES 100000
#define N_EDGES 1600000
#define F 128
#define OUT_CLS 40
#define LW 13          // waves per k_linear block
#define LBM (LW * 32)  // 416 rows per block -> grid 241 <= 256 CUs (single round)
#define BSHIFT 10      // coarse bucket = dst >> 10 (1024 nodes)
#define NBUCK 98       // ceil(100000/1024)
#define TILE 2048      // edges per k_bscatter block
#define ECAP 24576     // per-bucket ebuf segment capacity (mean 16384, sd~127 -> +64 sigma)

using f32x16 = __attribute__((ext_vector_type(16))) float;
using bf16x8 = __attribute__((ext_vector_type(8))) short;
using f16x2 = __attribute__((ext_vector_type(2))) _Float16;
using f16x8 = __attribute__((ext_vector_type(8))) _Float16;

// ---- edge accessor: flag=1 means int64 storage (little-endian low word at 2*idx) ----
__device__ __forceinline__ int edge_val(const int* eb, int is64, long idx) {
  return is64 ? eb[2 * idx] : eb[idx];
}

__global__ void k_detect(const unsigned int* eb, int* flag) {
  if (threadIdx.x == 0 && blockIdx.x == 0) {
    int is64 = 1;
#pragma unroll
    for (int i = 1; i < 16; i += 2) is64 &= (eb[i] == 0u);
    flag[0] = is64;
  }
}

// coarse scatter (single pass, no pre-histogram): LDS counting-sort a 2048-edge tile by
// bucket, reserve per-bucket runs in fixed-stride segments ebuf[b*ECAP ...] via one global
// atomic/bucket/tile, copy out coalesced. ebuf entry packed: src | (dst&1023)<<17.
// bkt_cursor starts at 0 and ends as the per-bucket edge count.
__global__ __launch_bounds__(256) void k_bscatter(const int* __restrict__ eb, const int* __restrict__ flag,
                                                  int* __restrict__ bkt_cursor, unsigned* __restrict__ ebuf) {
  __shared__ int lhist[128];
  __shared__ int lbase[128];
  __shared__ int gbase[NBUCK];
  __shared__ int lcnt[NBUCK];
  __shared__ unsigned buf[TILE];
  __shared__ int slotpos[TILE];
  int t = threadIdx.x;
  long e0 = (long)blockIdx.x * TILE;
  int is64 = flag[0];
  if (t < 128) lhist[t] = 0;
  __syncthreads();
#pragma unroll
  for (int i = 0; i < TILE / 256; ++i) {
    long e = e0 + t + i * 256;
    if (e < N_EDGES) {
      int d = edge_val(eb, is64, (long)N_EDGES + e);
      atomicAdd(&lhist[d >> BSHIFT], 1);
    }
  }
  __syncthreads();
  if (t < 128) lbase[t] = lhist[t];
  __syncthreads();
  for (int d = 1; d < 128; d <<= 1) {
    int v = (t >= d && t < 128) ? lbase[t - d] : 0;
    __syncthreads();
    if (t < 128) lbase[t] += v;
    __syncthreads();
  }
  if (t < NBUCK) {
    gbase[t] = atomicAdd(&bkt_cursor[t], lhist[t]);
    lcnt[t] = 0;
  }
  __syncthreads();
#pragma unroll
  for (int i = 0; i < TILE / 256; ++i) {
    long e = e0 + t + i * 256;
    if (e < N_EDGES) {
      int d = edge_val(eb, is64, (long)N_EDGES + e);
      int s = edge_val(eb, is64, e);
      int b = d >> BSHIFT;
      int n = atomicAdd(&lcnt[b], 1);
      int slot = lbase[b] - lhist[b] + n;
      buf[slot] = (unsigned)s | ((unsigned)(d & 1023) << 17);
      slotpos[slot] = b * ECAP + gbase[b] + n;
    }
  }
  __syncthreads();
  int tile_n = (int)min((long)TILE, (long)N_EDGES - e0);
  for (int i = t; i < tile_n; i += 256) {
    ebuf[slotpos[i]] = buf[i];
  }
}

// scan the 98 bucket counts (= bkt_cursor after bscatter) -> boff[0..98]; off[N]=N_EDGES
__global__ __launch_bounds__(128) void k_bscan2(const int* __restrict__ bkt_cursor, int* __restrict__ boff,
                                                int* __restrict__ off) {
  __shared__ int sh[128];
  int t = threadIdx.x;
  int v = (t < NBUCK) ? bkt_cursor[t] : 0;
  sh[t] = v;
  __syncthreads();
  for (int d = 1; d < 128; d <<= 1) {
    int u = (t >= d) ? sh[t - d] : 0;
    __syncthreads();
    sh[t] += u;
    __syncthreads();
  }
  int incl = sh[t];
  if (t < NBUCK) boff[t] = incl - v;
  if (t == NBUCK - 1) boff[NBUCK] = incl;
  if (t == 0) off[N_NODES] = N_EDGES;
}

// per-bucket fine sort: LDS 1024-bin histogram + wave-shuffle scan -> off[node], then
// LDS-cursor scatter of srcs. Reads the fixed-stride segment ebuf[b*ECAP ...].
__global__ __launch_bounds__(1024) void k_fsort(const unsigned* __restrict__ ebuf, const int* __restrict__ boff,
                                                int* __restrict__ off, int* __restrict__ srcs) {
  __shared__ int hist[1024];
  __shared__ int cur[1024];
  __shared__ int wsum[16];
  int b = blockIdx.x;
  int t = threadIdx.x;
  int p0 = boff[b], p1 = boff[b + 1];
  int cnt = p1 - p0;
  const unsigned* seg = ebuf + (size_t)b * ECAP;
  hist[t] = 0;
  __syncthreads();
  for (int p = t; p < cnt; p += 1024) {
    int d = (int)(seg[p] >> 17);
    atomicAdd(&hist[d], 1);
  }
  __syncthreads();
  // exclusive scan of hist[0..1024): per-wave shfl scan + wave-total scan
  int h = hist[t];
  int v = h;
#pragma unroll
  for (int o = 1; o < 64; o <<= 1) {
    int u = __shfl_up(v, o);
    if ((t & 63) >= o) v += u;
  }
  if ((t & 63) == 63) wsum[t >> 6] = v;
  __syncthreads();
  if (t < 64) {
    int w = (t < 16) ? wsum[t] : 0;
#pragma unroll
    for (int o = 1; o < 16; o <<= 1) {
      int u = __shfl_up(w, o);
      if (t >= o) w += u;
    }
    if (t < 16) wsum[t] = w;
  }
  __syncthreads();
  int base = (t >> 6) ? wsum[(t >> 6) - 1] : 0;
  int gpos = p0 + base + v - h;  // exclusive prefix
  int node = (b << BSHIFT) + t;
  if (node < N_NODES) off[node] = gpos;
  cur[t] = gpos;
  __syncthreads();
  for (int p = t; p < cnt; p += 1024) {
    unsigned e = seg[p];
    int pos = atomicAdd(&cur[(int)(e >> 17)], 1);
    srcs[pos] = (int)(e & 0x1FFFFu);
  }
}

// fp32 -> fp16 copy (RN), 8 elems/thread, row-major
__global__ __launch_bounds__(256) void k_tohalf(const float* __restrict__ in, _Float16* __restrict__ o) {
  int i = blockIdx.x * 256 + threadIdx.x;
  if (i >= N_NODES * F / 8) return;
  float4 a = reinterpret_cast<const float4*>(in)[2 * i];
  float4 b = reinterpret_cast<const float4*>(in)[2 * i + 1];
  union {
    _Float16 h[8];
    uint4 u;
  } r;
  r.h[0] = (_Float16)a.x; r.h[1] = (_Float16)a.y; r.h[2] = (_Float16)a.z; r.h[3] = (_Float16)a.w;
  r.h[4] = (_Float16)b.x; r.h[5] = (_Float16)b.y; r.h[6] = (_Float16)b.z; r.h[7] = (_Float16)b.w;
  reinterpret_cast<uint4*>(o)[i] = r.u;
}

// one wave per node, fp16 row gather; lane l owns features [2l, 2l+1]; fp32 accumulate,
// fp16 mean output. (Fetch-path-bound at ~3.6 TB/s — compulsory per-XCD distinct-row floor;
// R4 MLP-doubling null, R5 slice overhead 4x, R8 fusion kills TLP.)
__global__ __launch_bounds__(256) void k_aggregate(const _Float16* __restrict__ x, const int* __restrict__ off,
                                                   const int* __restrict__ srcs, _Float16* __restrict__ agg16) {
  int n = blockIdx.x * 4 + (threadIdx.x >> 6);
  if (n >= N_NODES) return;
  int l = threadIdx.x & 63;
  int p0 = off[n], p1 = off[n + 1];
  int deg = p1 - p0;
  float sx = 0.f, sy = 0.f;

  for (int base = 0; base < deg; base += 64) {
    int rem = deg - base;
    int cnt = (rem < 64) ? rem : 64;
    int my = (l < cnt) ? srcs[p0 + base + l] : 0;
    int j = 0;
    for (; j + 7 < cnt; j += 8) {
      int s[8];
#pragma unroll
      for (int k = 0; k < 8; ++k) s[k] = __builtin_amdgcn_readlane(my, j + k);
      f16x2 v[8];
#pragma unroll
      for (int k = 0; k < 8; ++k)
        v[k] = *reinterpret_cast<const f16x2*>(x + (size_t)(unsigned)s[k] * F + 2 * l);
#pragma unroll
      for (int k = 0; k < 8; ++k) {
        sx += (float)v[k][0];
        sy += (float)v[k][1];
      }
    }
    for (; j + 3 < cnt; j += 4) {
      int s[4];
#pragma unroll
      for (int k = 0; k < 4; ++k) s[k] = __builtin_amdgcn_readlane(my, j + k);
      f16x2 v[4];
#pragma unroll
      for (int k = 0; k < 4; ++k)
        v[k] = *reinterpret_cast<const f16x2*>(x + (size_t)(unsigned)s[k] * F + 2 * l);
#pragma unroll
      for (int k = 0; k < 4; ++k) {
        sx += (float)v[k][0];
        sy += (float)v[k][1];
      }
    }
    for (; j < cnt; ++j) {
      int s = __builtin_amdgcn_readlane(my, j);
      f16x2 v = *reinterpret_cast<const f16x2*>(x + (size_t)(unsigned)s * F + 2 * l);
      sx += (float)v[0];
      sy += (float)v[1];
    }
  }

  float inv = 1.0f / (float)max(deg, 1);
  f16x2 r;
  r[0] = (_Float16)(sx * inv);
  r[1] = (_Float16)(sy * inv);
  *reinterpret_cast<f16x2*>(agg16 + (size_t)n * F + 2 * l) = r;
}

// fp16x8 -> bf16-hi truncation (for the weight-delta MFMA term; cross error ~2^-21)
__device__ __forceinline__ bf16x8 to_bf16hi(const f16x8& v) {
  bf16x8 r;
#pragma unroll
  for (int i = 0; i < 8; ++i) {
    union { float f; unsigned u; } t;
    t.f = (float)v[i];
    r[i] = (short)(t.u >> 16);
  }
  return r;
}

// pre-split weights: per layer -> wsp[layer][4][128*128] planes:
// [0]=Wl_hi(fp16 RN), [1]=Wl_delta(bf16 of w - fp16(w)), [2]=Wr_hi(fp16), [3]=Wr_delta(bf16).
// delta magnitude ~2^-12|w| -> bf16-normal range (no MFMA denormal risk); total W precision
// ~19 bits (vs 16 for the old bf16 hi/lo pair).
__global__ __launch_bounds__(256) void k_wsplit(const float* __restrict__ Wl1, const float* __restrict__ Wr1,
                                                const float* __restrict__ Wl2, const float* __restrict__ Wr2,
                                                const float* __restrict__ Wl3, const float* __restrict__ Wr3,
                                                unsigned short* __restrict__ wsp) {
  int e = blockIdx.x * 256 + threadIdx.x;  // 0..49151
  if (e >= 3 * 16384) return;
  int L = e >> 14, off = e & 16383;
  const float* wl = (L == 0) ? Wl1 : (L == 1) ? Wl2 : Wl3;
  const float* wr = (L == 0) ? Wr1 : (L == 1) ? Wr2 : Wr3;
  unsigned short* base = wsp + (size_t)L * 4 * 16384;
  {
    float wv = wl[off];
    _Float16 h = (_Float16)wv;
    union { _Float16 h; unsigned short u; } hb;
    hb.h = h;
    union { float f; unsigned u; } d;
    d.f = wv - (float)h;
    base[off] = hb.u;
    base[16384 + off] = (unsigned short)(d.u >> 16);
  }
  {
    float wv = wr[off];
    _Float16 h = (_Float16)wv;
    union { _Float16 h; unsigned short u; } hb;
    hb.h = h;
    union { float f; unsigned u; } d;
    d.f = wv - (float)h;
    base[2 * 16384 + off] = hb.u;
    base[3 * 16384 + off] = (unsigned short)(d.u >> 16);
  }
}

// out[n][j] = normalize(dot(agg[n],Wl[j]) + dot(x[n],Wr[j]) + bl[j]) [+relu].
// fp16 activations consumed DIRECTLY by f16-MFMA (zero repack VALU) against fp16 W-hi;
// bf16-delta correction term uses bf16-hi of activations. 4 MFMAs/(ks,ct) vs old 6,
// VALU/ks ~32 vs ~96 -> MFMA-pipe-bound instead of repack-bound.
__global__ __launch_bounds__(832, 1) void k_linear(const _Float16* __restrict__ agg16,
                                                   const _Float16* __restrict__ x16,
                                                   const unsigned short* __restrict__ wsp,  // [4][128][128]
                                                   const float* __restrict__ bl, float* __restrict__ out,
                                                   _Float16* __restrict__ out16, int relu) {
  __shared__ unsigned short wlds[4][128][136];  // +8 pad: b128 frag reads ~2-way max
  int tid = threadIdx.x;

  for (int c = tid; c < 4 * 2048; c += 832) {
    int m = c >> 11, rem = c & 2047;
    int j = rem >> 4, kc = (rem & 15) * 8;
    uint4 v = *reinterpret_cast<const uint4*>(wsp + (size_t)m * 16384 + j * 128 + kc);
    *reinterpret_cast<uint4*>(&wlds[m][j][kc]) = v;
  }
  __syncthreads();

  int wid = tid >> 6, lane = tid & 63;
  int l31 = lane & 31, lhi = lane >> 5;
  long rb = (long)blockIdx.x * LBM + (long)wid * 32;
  if (rb >= N_NODES) return;  // whole-wave out of range (after barrier)

  int r0 = (int)min(rb + l31, (long)N_NODES - 1);
  const _Float16* a0p = agg16 + (size_t)r0 * F + lhi * 8;
  const _Float16* x0p = x16 + (size_t)r0 * F + lhi * 8;

  f32x16 acc[4];
#pragma unroll
  for (int ct = 0; ct < 4; ++ct) acc[ct] = (f32x16)0.f;

  f16x8 av = *reinterpret_cast<const f16x8*>(a0p);
  f16x8 xv = *reinterpret_cast<const f16x8*>(x0p);

#pragma unroll
  for (int ks = 0; ks < 8; ++ks) {
    f16x8 av_n, xv_n;
    if (ks < 7) {
      av_n = *reinterpret_cast<const f16x8*>(a0p + (ks + 1) * 16);
      xv_n = *reinterpret_cast<const f16x8*>(x0p + (ks + 1) * 16);
    }
    int k0 = ks * 16 + lhi * 8;
    bf16x8 avb = to_bf16hi(av);
    bf16x8 xvb = to_bf16hi(xv);
#pragma unroll
    for (int ct = 0; ct < 4; ++ct) {
      int j = ct * 32 + l31;
      f16x8 BlH = *reinterpret_cast<const f16x8*>(&wlds[0][j][k0]);
      bf16x8 BlD = *reinterpret_cast<const bf16x8*>(&wlds[1][j][k0]);
      f16x8 BrH = *reinterpret_cast<const f16x8*>(&wlds[2][j][k0]);
      bf16x8 BrD = *reinterpret_cast<const bf16x8*>(&wlds[3][j][k0]);
      acc[ct] = __builtin_amdgcn_mfma_f32_32x32x16_f16(av, BlH, acc[ct], 0, 0, 0);
      acc[ct] = __builtin_amdgcn_mfma_f32_32x32x16_bf16(avb, BlD, acc[ct], 0, 0, 0);
      acc[ct] = __builtin_amdgcn_mfma_f32_32x32x16_f16(xv, BrH, acc[ct], 0, 0, 0);
      acc[ct] = __builtin_amdgcn_mfma_f32_32x32x16_bf16(xvb, BrD, acc[ct], 0, 0, 0);
    }
    av = av_n;
    xv = xv_n;
  }

  // epilogue: +bias, row L2-norm across 32 lanes (same lhi), optional relu, masked store.
#pragma unroll
  for (int ct = 0; ct < 4; ++ct) {
    float b = bl[ct * 32 + l31];
#pragma unroll
    for (int i = 0; i < 16; ++i) acc[ct][i] += b;
  }
#pragma unroll
  for (int i = 0; i < 16; ++i) {
    float ss = acc[0][i] * acc[0][i] + acc[1][i] * acc[1][i] +
               acc[2][i] * acc[2][i] + acc[3][i] * acc[3][i];
#pragma unroll
    for (int o = 1; o < 32; o <<= 1) ss += __shfl_xor(ss, o);
    float inv = 1.0f / fmaxf(sqrtf(ss), 1e-12f);
    long grow = rb + (i & 3) + 8 * (i >> 2) + 4 * lhi;
    if (grow < N_NODES) {
      long base = grow * F + l31;
#pragma unroll
      for (int ct = 0; ct < 4; ++ct) {
        float v = acc[ct][i] * inv;
        if (relu) v = fmaxf(v, 0.f);
        if (out) out[base + ct * 32] = v;
        if (out16) out16[base + ct * 32] = (_Float16)v;
      }
    }
  }
}

// 32 nodes/block (grid = N_NODES/32 = 3125); Wfc + h tile in LDS; 8 threads/node x 5 classes.
// h read from the fp16 copy (layer-3 fp32 round-trip eliminated, ~50MB saved).
#define FCP 132
__global__ __launch_bounds__(256) void k_fc_softmax(const _Float16* __restrict__ h, const float* __restrict__ Wfc,
                                                    const float* __restrict__ bfc, float* __restrict__ out) {
  __shared__ float w_s[OUT_CLS][FCP];
  __shared__ float h_s[32][FCP];
  int tid = threadIdx.x;
  int nb = blockIdx.x * 32;

  for (int i = tid; i < OUT_CLS * (F / 4); i += 256) {
    int r = i >> 5, c = (i & 31) * 4;
    *reinterpret_cast<float4*>(&w_s[r][c]) = *reinterpret_cast<const float4*>(Wfc + (size_t)r * F + c);
  }
  for (int i = tid; i < 32 * (F / 8); i += 256) {
    int r = i >> 4, c = (i & 15) * 8;
    f16x8 v = *reinterpret_cast<const f16x8*>(h + (size_t)(nb + r) * F + c);
#pragma unroll
    for (int k = 0; k < 8; ++k) h_s[r][c + k] = (float)v[k];
  }
  __syncthreads();

  int r = tid >> 3, sub = tid & 7;
  float acc[5];
#pragma unroll
  for (int c = 0; c < 5; ++c) acc[c] = bfc[sub * 5 + c];

  for (int k4 = 0; k4 < F / 4; ++k4) {
    float4 hv = *reinterpret_cast<const float4*>(&h_s[r][k4 * 4]);
#pragma unroll
    for (int c = 0; c < 5; ++c) {
      float4 wv = *reinterpret_cast<const float4*>(&w_s[sub * 5 + c][k4 * 4]);
      acc[c] += hv.x * wv.x + hv.y * wv.y + hv.z * wv.z + hv.w * wv.w;
    }
  }

  float m = acc[0];
#pragma unroll
  for (int c = 1; c < 5; ++c) m = fmaxf(m, acc[c]);
#pragma unroll
  for (int o = 4; o > 0; o >>= 1) m = fmaxf(m, __shfl_xor(m, o));
  float e[5], s = 0.f;
#pragma unroll
  for (int c = 0; c < 5; ++c) {
    e[c] = expf(acc[c] - m);
    s += e[c];
  }
#pragma unroll
  for (int o = 4; o > 0; o >>= 1) s += __shfl_xor(s, o);
  float inv = 1.0f / s;
#pragma unroll
  for (int c = 0; c < 5; ++c) out[(size_t)(nb + r) * OUT_CLS + sub * 5 + c] = e[c] * inv;
}

extern "C" void kernel_launch(void* const* d_in, const int* in_sizes, int n_in, void* d_out, int out_size,
                              void* d_ws, size_t ws_size, hipStream_t stream) {
  const float* feat = (const float*)d_in[0];
  const int* eb = (const int*)d_in[1];
  const float* Wl1 = (const float*)d_in[2];
  const float* bl1 = (const float*)d_in[3];
  const float* Wr1 = (const float*)d_in[4];
  const float* Wl2 = (const float*)d_in[5];
  const float* bl2 = (const float*)d_in[6];
  const float* Wr2 = (const float*)d_in[7];
  const float* Wl3 = (const float*)d_in[8];
  const float* bl3 = (const float*)d_in[9];
  const float* Wr3 = (const float*)d_in[10];
  const float* Wfc = (const float*)d_in[11];
  const float* bfc = (const float*)d_in[12];
  float* out = (float*)d_out;

  char* w = (char*)d_ws;
  auto alloc = [&](size_t bytes) {
    char* p = w;
    w += (bytes + 255) & ~(size_t)255;
    return p;
  };
  int* flag = (int*)alloc(4);
  int* boff = (int*)alloc((size_t)(NBUCK + 1) * 4);
  int* off = (int*)alloc((size_t)(N_NODES + 1) * 4);
  int* srcs = (int*)alloc((size_t)N_EDGES * 4 + 256);  // +pad
  int* bkt_cursor = (int*)alloc((size_t)NBUCK * 4);
  unsigned short* wsp = (unsigned short*)alloc((size_t)3 * 4 * 16384 * 2);
  unsigned* ebuf = (unsigned*)alloc((size_t)NBUCK * ECAP * 4);     // 9.6MB
  _Float16* agg16 = (_Float16*)alloc((size_t)N_NODES * F * 2);     // gather output
  _Float16* h16X = (_Float16*)alloc((size_t)N_NODES * F * 2);      // feat16, later h2_16
  _Float16* h16A = (_Float16*)alloc((size_t)N_NODES * F * 2);      // h1_16, later h3_16
  (void)ws_size;
  (void)in_sizes;
  (void)n_in;
  (void)out_size;

  hipMemsetAsync(bkt_cursor, 0, (size_t)NBUCK * 4, stream);
  k_detect<<<1, 64, 0, stream>>>((const unsigned int*)eb, flag);
  k_bscatter<<<(N_EDGES + TILE - 1) / TILE, 256, 0, stream>>>(eb, flag, bkt_cursor, ebuf);
  k_bscan2<<<1, 128, 0, stream>>>(bkt_cursor, boff, off);
  k_fsort<<<NBUCK, 1024, 0, stream>>>(ebuf, boff, off, srcs);
  k_wsplit<<<192, 256, 0, stream>>>(Wl1, Wr1, Wl2, Wr2, Wl3, Wr3, wsp);
  k_tohalf<<<(N_NODES * F / 8 + 255) / 256, 256, 0, stream>>>(feat, h16X);

  const int nag = (N_NODES + 3) / 4;           // one wave per node
  const int nlin = (N_NODES + LBM - 1) / LBM;  // 241 (single round on 256 CUs)
  const int nfc = N_NODES / 32;                // 3125

  // layer 1: gather h16X(feat16) -> agg16; linear(agg16, x16=h16X) -> h16A
  k_aggregate<<<nag, 256, 0, stream>>>(h16X, off, srcs, agg16);
  k_linear<<<nlin, 832, 0, stream>>>(agg16, h16X, wsp + 0 * 4 * 16384, bl1, ((float*)0), h16A, 1);
  // layer 2: gather h16A -> agg16; linear(agg16, x16=h16A) -> h16X (h2_16)
  k_aggregate<<<nag, 256, 0, stream>>>(h16A, off, srcs, agg16);
  k_linear<<<nlin, 832, 0, stream>>>(agg16, h16A, wsp + 1 * 4 * 16384, bl2, ((float*)0), h16X, 1);
  // layer 3: gather h16X -> agg16; linear(agg16, x16=h16X) -> h16A (h3_16, fp16 only)
  k_aggregate<<<nag, 256, 0, stream>>>(h16X, off, srcs, agg16);
  k_linear<<<nlin, 832, 0, stream>>>(agg16, h16X, wsp + 2 * 4 * 16384, bl3, ((float*)0), h16A, 0);
  // FC + softmax (reads fp16 h)
  k_fc_softmax<<<nfc, 256, 0, stream>>>(h16A, Wfc, bfc, out);
}